// Round 13
// baseline (2287.147 us; speedup 1.0000x reference)
//
#include <hip/hip_runtime.h>
#include <math.h>

#define NN      65536
#define KNN     12
#define WIDTH   256
#define GW      192
#define DEPTH   7
#define GLAYERS 4
#define FF      48

// seed grid (SAT): 192^3 cells over [-6,6]^3, cell 0.0625
#define GC    192
#define GC3   7077888
#define GLO   (-6.0f)
#define GCW   0.0625f
#define GINV  16.0f

// sort grid: 64^3 cells for counting sort (groups of 64 sorted points)
#define GC2     64
#define GC2_3   262144
#define GINV2   5.3333333f
#define NG      1024          // NN/64 groups
#define SEGW    4             // group-loop split across the block's 4 waves
#define CAPS    384           // per-(query,seg) cap; per-seg <= total <= 384 (R9)

typedef __attribute__((ext_vector_type(8))) _Float16 half8;
typedef __attribute__((ext_vector_type(4))) _Float16 half4;
typedef __attribute__((ext_vector_type(4))) float    f4;

__device__ __forceinline__ float silu_f(float v) { return v / (1.0f + expf(-v)); }

// top-12 ladder on NAMED scalars (phase-2 only)
#define KSWAP(A,B,IA,IB) do { if (B < A) { float _t=A; A=B; B=_t; int _u=IA; IA=IB; IB=_u; } } while(0)
#define KINSERT(DV,IV) do { b11=(DV); j11=(IV); \
    KSWAP(b10,b11,j10,j11); KSWAP(b9,b10,j9,j10); KSWAP(b8,b9,j8,j9); \
    KSWAP(b7,b8,j7,j8);  KSWAP(b6,b7,j6,j7);  KSWAP(b5,b6,j5,j6); \
    KSWAP(b4,b5,j4,j5);  KSWAP(b3,b4,j3,j4);  KSWAP(b2,b3,j2,j3); \
    KSWAP(b1,b2,j1,j2);  KSWAP(b0,b1,j0,j1); } while(0)

// ---------------- prep: pack x + |x|^2 as float4 ----------------
__global__ __launch_bounds__(256) void prep_xw_kernel(const float* __restrict__ x,
                                                      float4* __restrict__ xw) {
    int i = blockIdx.x * 256 + threadIdx.x;
    float a = x[3*i], b = x[3*i+1], c = x[3*i+2];
    xw[i] = make_float4(a, b, c, a*a + b*b + c*c);
}

// ---------------- generic zero (int4 per thread) ----------------
__global__ __launch_bounds__(256) void zero_cnt_kernel(int* __restrict__ cnt) {
    int g = blockIdx.x*256 + threadIdx.x;
    *(int4*)&cnt[g*4] = make_int4(0,0,0,0);
}

__device__ __forceinline__ int cell_of(float v) {
    int c = (int)floorf((v - GLO) * GINV);
    return min(max(c, 0), GC-1);
}
__device__ __forceinline__ int cell2_of(float v) {
    int c = (int)floorf((v - GLO) * GINV2);
    return min(max(c, 0), GC2-1);
}

// ---------------- 192^3 hist + 3-pass in-place SAT + per-query seed bound ----------------
__global__ __launch_bounds__(256) void hist_kernel(const float4* __restrict__ xw,
                                                   int* __restrict__ cnt) {
    int i = blockIdx.x*256 + threadIdx.x;
    float4 p = xw[i];
    atomicAdd(&cnt[(cell_of(p.z)*GC + cell_of(p.y))*GC + cell_of(p.x)], 1);
}

__global__ __launch_bounds__(256) void satx_kernel(int* __restrict__ S) {
    int zy = blockIdx.x*256 + threadIdx.x;
    int base = zy * GC, run = 0;
    for (int i = 0; i < GC; ++i) { run += S[base+i]; S[base+i] = run; }
}
__global__ __launch_bounds__(256) void saty_kernel(int* __restrict__ S) {
    int t = blockIdx.x*256 + threadIdx.x;
    int z = t / GC, xx = t % GC, run = 0;
    for (int y = 0; y < GC; ++y) { int idx = (z*GC + y)*GC + xx; run += S[idx]; S[idx] = run; }
}
__global__ __launch_bounds__(256) void satz_kernel(int* __restrict__ S) {
    int t = blockIdx.x*256 + threadIdx.x;
    int y = t / GC, xx = t % GC, run = 0;
    for (int z = 0; z < GC; ++z) { int idx = (z*GC + y)*GC + xx; run += S[idx]; S[idx] = run; }
}

__device__ __forceinline__ int satv(const int* __restrict__ S, int xx, int y, int z) {
    if (xx < 0 || y < 0 || z < 0) return 0;
    return S[(z*GC + y)*GC + xx];
}

__global__ __launch_bounds__(256) void seed_kernel(const float4* __restrict__ xw,
                                                   const int* __restrict__ S,
                                                   float* __restrict__ seed) {
    int q = blockIdx.x*256 + threadIdx.x;
    float4 me = xw[q];
    int cx = cell_of(me.x), cy = cell_of(me.y), cz = cell_of(me.z);
    for (int R = 1; R < GC; ++R) {
        int x0 = max(cx-R, 0), x1 = min(cx+R, GC-1);
        int y0 = max(cy-R, 0), y1 = min(cy+R, GC-1);
        int z0 = max(cz-R, 0), z1 = min(cz+R, GC-1);
        int c = satv(S,x1,y1,z1) - satv(S,x0-1,y1,z1) - satv(S,x1,y0-1,z1) - satv(S,x1,y1,z0-1)
              + satv(S,x0-1,y0-1,z1) + satv(S,x0-1,y1,z0-1) + satv(S,x1,y0-1,z0-1)
              - satv(S,x0-1,y0-1,z0-1);
        if (c >= KNN + 1) {
            float dx = fmaxf(me.x - (GLO + x0*GCW), (GLO + (x1+1)*GCW) - me.x);
            float dy = fmaxf(me.y - (GLO + y0*GCW), (GLO + (y1+1)*GCW) - me.y);
            float dz = fmaxf(me.z - (GLO + z0*GCW), (GLO + (z1+1)*GCW) - me.z);
            seed[q] = (dx*dx + dy*dy + dz*dz) * 1.00002f + 1e-6f;
            return;
        }
    }
    seed[q] = 3e38f;
}

// ---------------- 64^3 counting sort: hist2, scan x3, scatter ----------------
__global__ __launch_bounds__(256) void hist2_kernel(const float4* __restrict__ xw,
                                                    int* __restrict__ cnt2,
                                                    int* __restrict__ pcell,
                                                    int* __restrict__ prank) {
    int i = blockIdx.x*256 + threadIdx.x;
    float4 p = xw[i];
    int c = (cell2_of(p.z)*GC2 + cell2_of(p.y))*GC2 + cell2_of(p.x);
    pcell[i] = c;
    prank[i] = atomicAdd(&cnt2[c], 1);
}

__global__ __launch_bounds__(256) void scan1_kernel(const int* __restrict__ cnt,
                                                    int* __restrict__ start,
                                                    int* __restrict__ sums) {
    __shared__ int lds[256];
    const int tid = threadIdx.x;
    int base = blockIdx.x*1024 + tid*4;
    int4 v = *(const int4*)&cnt[base];
    int s0 = v.x, s01 = v.x+v.y, s012 = s01+v.z, tot = s012+v.w;
    lds[tid] = tot; __syncthreads();
    for (int off = 1; off < 256; off <<= 1) {
        int t = (tid >= off) ? lds[tid-off] : 0;
        __syncthreads();
        lds[tid] += t;
        __syncthreads();
    }
    int excl = lds[tid] - tot;
    int4 o; o.x = excl; o.y = excl+s0; o.z = excl+s01; o.w = excl+s012;
    *(int4*)&start[base] = o;
    if (tid == 255) sums[blockIdx.x] = lds[255];
}

__global__ __launch_bounds__(256) void scan2_kernel(int* __restrict__ sums) {
    __shared__ int lds[256];
    const int tid = threadIdx.x;
    int v = sums[tid];
    lds[tid] = v; __syncthreads();
    for (int off = 1; off < 256; off <<= 1) {
        int t = (tid >= off) ? lds[tid-off] : 0;
        __syncthreads();
        lds[tid] += t;
        __syncthreads();
    }
    sums[tid] = lds[tid] - v;   // exclusive
}

__global__ __launch_bounds__(256) void scan3_kernel(int* __restrict__ start,
                                                    const int* __restrict__ sums) {
    int g = blockIdx.x*256 + threadIdx.x;
    start[g] += sums[g >> 10];
}

__global__ __launch_bounds__(256) void scatter_kernel(const float4* __restrict__ xw,
                                                      const int* __restrict__ pcell,
                                                      const int* __restrict__ prank,
                                                      const int* __restrict__ start,
                                                      float4* __restrict__ xs,
                                                      int* __restrict__ sidx) {
    int i = blockIdx.x*256 + threadIdx.x;
    int p = start[pcell[i]] + prank[i];
    xs[p] = xw[i];
    sidx[p] = i;
}

// ---------------- group bboxes: 64 sorted points per group ----------------
__global__ __launch_bounds__(64) void gbox_kernel(const float4* __restrict__ xs,
                                                  float4* __restrict__ gbox) {
    __shared__ float mn[3][64];
    __shared__ float mx[3][64];
    const int g = blockIdx.x, t = threadIdx.x;
    float4 p = xs[g*64 + t];
    mn[0][t]=p.x; mn[1][t]=p.y; mn[2][t]=p.z;
    mx[0][t]=p.x; mx[1][t]=p.y; mx[2][t]=p.z;
    __syncthreads();
    for (int off = 32; off >= 1; off >>= 1) {
        if (t < off) {
#pragma unroll
            for (int a = 0; a < 3; ++a) {
                mn[a][t] = fminf(mn[a][t], mn[a][t+off]);
                mx[a][t] = fmaxf(mx[a][t], mx[a][t+off]);
            }
        }
        __syncthreads();
    }
    if (t == 0) {
        gbox[2*g]   = make_float4(mn[0][0], mn[1][0], mn[2][0], 0.f);
        gbox[2*g+1] = make_float4(mx[0][0], mx[1][0], mx[2][0], 0.f);
    }
}

// ---------------- kNN phase 1: seed-ball group scan, 4-wave split ----------------
// Block = 64 queries (one per lane; all 4 waves share them). Wave w scans group
// quarter [256w,256w+256). Grid = NN/64 = 1024 blocks -> 16 waves/CU (R12's
// failure was 1 wave/SIMD: grid ceiling at NN/64 total waves with no split).
// accept iff me.c - 0.5*c.w > ht  (same fp form as R9-R11 passing runs).
// pairs layout [seg][slot][gid]: same-slot lanes write 128 B contiguous.
__global__ __launch_bounds__(256) void knn_ball_kernel(const float4* __restrict__ xs,
                                                       const int* __restrict__ sidx,
                                                       const float* __restrict__ seed,
                                                       const float4* __restrict__ gbox,
                                                       unsigned short* __restrict__ pairs,
                                                       unsigned short* __restrict__ pcnt) {
    __shared__ float4 gb[NG*2];    // 32 KB (4 blocks/CU -> 128 KB < 160)
    const int tid = threadIdx.x;
    for (int k = tid; k < NG*2; k += 256) gb[k] = gbox[k];
    __syncthreads();
    const int lane = tid & 63, wv = tid >> 6;
    const int gid = blockIdx.x*64 + lane;
    const float4 me = xs[gid];
    const int q = sidx[gid];
    const float sd = seed[q];
    const float ht = -0.5f*(sd - me.w + 1e-3f);
    const float r2m = sd + 2e-3f;   // conservative box-prune bound (> accept slop)
    int cnt = 0;
    const size_t segbase = (size_t)wv*CAPS*NN + gid;
    const int g0 = wv*(NG/SEGW), g1 = g0 + NG/SEGW;
    for (int g = g0; g < g1; ++g) {
        float4 bmin = gb[2*g], bmax = gb[2*g+1];
        float dx = fmaxf(fmaxf(bmin.x - me.x, me.x - bmax.x), 0.f);
        float dy = fmaxf(fmaxf(bmin.y - me.y, me.y - bmax.y), 0.f);
        float dz = fmaxf(fmaxf(bmin.z - me.z, me.z - bmax.z), 0.f);
        float md = fmaf(dx, dx, fmaf(dy, dy, dz*dz));
        bool hit = md < r2m;
        if (__any(hit)) {
            if (hit) {
                const float4* gp = xs + g*64;
                const int* sp = sidx + g*64;
#pragma unroll 4
                for (int j = 0; j < 64; ++j) {
                    float4 c = gp[j];          // uniform addr among active lanes
                    float s = fmaf(me.x, c.x, fmaf(me.y, c.y, fmaf(me.z, c.z, -0.5f*c.w)));
                    if (s > ht) {
                        int osrc = sp[j];
                        if (osrc != q) {
                            if (cnt < CAPS) pairs[segbase + (size_t)cnt*NN] = (unsigned short)osrc;
                            ++cnt;
                        }
                    }
                }
            }
        }
    }
    pcnt[wv*NN + gid] = (unsigned short)(cnt < CAPS ? cnt : CAPS);
}

// ---------------- kNN phase 2: exact top-12 over 4 merged seg lists ----------------
__global__ __launch_bounds__(256) void knn_topk_kernel(const float4* __restrict__ xw,
                                                       const float4* __restrict__ xs,
                                                       const int* __restrict__ sidx,
                                                       const unsigned short* __restrict__ pcnt,
                                                       const unsigned short* __restrict__ pairs,
                                                       int* __restrict__ knn_idx) {
    const int gid = blockIdx.x * 256 + threadIdx.x;
    const float4 me = xs[gid];
    const int q = sidx[gid];
    const float qsq = me.w;
    float b0=3e38f,b1=3e38f,b2=3e38f,b3=3e38f,b4=3e38f,b5=3e38f,
          b6=3e38f,b7=3e38f,b8=3e38f,b9=3e38f,b10=3e38f,b11=3e38f;
    int   j0=-1,j1=-1,j2=-1,j3=-1,j4=-1,j5=-1,j6=-1,j7=-1,j8=-1,j9=-1,j10=-1,j11=-1;
    for (int s = 0; s < SEGW; ++s) {
        const int n = pcnt[s*NN + gid];
        const size_t base = (size_t)s*CAPS*NN + gid;
        for (int i = 0; i < n; ++i) {
            int idx = pairs[base + (size_t)i*NN];   // coalesced across lanes
            float4 c = xw[idx];
            float dot = me.x*c.x + me.y*c.y + me.z*c.z;
            float d = fmaf(-2.0f, dot, qsq + c.w); // EXACT ref formula
            d = fmaxf(d, 0.0f);                    // ref clips at 0
            if (d < b11) KINSERT(d, idx);
        }
    }
    knn_idx[q*KNN+0]=j0;  knn_idx[q*KNN+1]=j1;  knn_idx[q*KNN+2]=j2;
    knn_idx[q*KNN+3]=j3;  knn_idx[q*KNN+4]=j4;  knn_idx[q*KNN+5]=j5;
    knn_idx[q*KNN+6]=j6;  knn_idx[q*KNN+7]=j7;  knn_idx[q*KNN+8]=j8;
    knn_idx[q*KNN+9]=j9;  knn_idx[q*KNN+10]=j10; knn_idx[q*KNN+11]=j11;
}

// ---------------- weight convert+transpose to f16 [N][K] ----------------
__global__ __launch_bounds__(256) void convert_Wt_kernel(const float* __restrict__ W,
                                                         _Float16* __restrict__ Wt) {
    int e = blockIdx.x*256 + threadIdx.x;
    int l = e >> 16, r = e & 65535;
    int n = r >> 8, k = r & 255;
    Wt[(size_t)l*65536 + n*256 + k] = (_Float16)W[(size_t)l*65536 + k*256 + n];
}

__global__ __launch_bounds__(256) void convert_Bg_kernel(const float* __restrict__ Ws,
                                                         const float* __restrict__ Wn,
                                                         _Float16* __restrict__ Bg) {
    int e = blockIdx.x*256 + threadIdx.x;
    int l = e / 73728, r = e % 73728;
    int n = r / 384, k = r % 384;
    float v = (k < 192) ? Ws[(size_t)l*36864 + k*192 + n]
                        : Wn[(size_t)l*36864 + (k-192)*192 + n];
    Bg[(size_t)l*73728 + (size_t)n*384 + k] = (_Float16)v;
}

__global__ __launch_bounds__(256) void convert_Wgo_kernel(const float* __restrict__ Wg_out,
                                                          _Float16* __restrict__ Wgo) {
    int e = blockIdx.x*256 + threadIdx.x;
    int n = e / 192, k = e % 192;
    Wgo[e] = (_Float16)Wg_out[k*256 + n];
}

// ---------------- fourier features + both input layers (f16 out) ----------------
__global__ __launch_bounds__(256) void fourier_input_kernel(
    const float* __restrict__ x, const float* __restrict__ Bf,
    const float* __restrict__ W_in, const float* __restrict__ b_in,
    const float* __restrict__ Wg_in, const float* __restrict__ bg_in,
    _Float16* __restrict__ h0, _Float16* __restrict__ g0) {
    const int n = blockIdx.x * 256 + threadIdx.x;
    const float x0 = x[3*n], x1 = x[3*n+1], x2 = x[3*n+2];
    float ff[FF];
#pragma unroll
    for (int sm = 0; sm < 24; ++sm) {
        int s = sm >> 3, m = sm & 7;
        float p = x0*Bf[s*24 + m] + x1*Bf[s*24 + 8 + m] + x2*Bf[s*24 + 16 + m];
        float sv, cv; sincosf(p, &sv, &cv);
        ff[sm] = sv; ff[24 + sm] = cv;
    }
    {
        const float4* W4 = (const float4*)W_in;
        const float4* b4 = (const float4*)b_in;
#pragma unroll 2
        for (int j4 = 0; j4 < WIDTH/4; ++j4) {
            float4 acc = b4[j4];
#pragma unroll
            for (int k = 0; k < FF; ++k) {
                float4 w = W4[k*(WIDTH/4) + j4]; float f = ff[k];
                acc.x = fmaf(f, w.x, acc.x); acc.y = fmaf(f, w.y, acc.y);
                acc.z = fmaf(f, w.z, acc.z); acc.w = fmaf(f, w.w, acc.w);
            }
            half4 o;
            o[0] = (_Float16)silu_f(acc.x); o[1] = (_Float16)silu_f(acc.y);
            o[2] = (_Float16)silu_f(acc.z); o[3] = (_Float16)silu_f(acc.w);
            *(half4*)&h0[(size_t)n*WIDTH + j4*4] = o;
        }
    }
    {
        const float4* W4 = (const float4*)Wg_in;
        const float4* b4 = (const float4*)bg_in;
#pragma unroll 2
        for (int j4 = 0; j4 < GW/4; ++j4) {
            float4 acc = b4[j4];
#pragma unroll
            for (int k = 0; k < FF; ++k) {
                float4 w = W4[k*(GW/4) + j4]; float f = ff[k];
                acc.x = fmaf(f, w.x, acc.x); acc.y = fmaf(f, w.y, acc.y);
                acc.z = fmaf(f, w.z, acc.z); acc.w = fmaf(f, w.w, acc.w);
            }
            half4 o;
            o[0] = (_Float16)silu_f(acc.x); o[1] = (_Float16)silu_f(acc.y);
            o[2] = (_Float16)silu_f(acc.z); o[3] = (_Float16)silu_f(acc.w);
            *(half4*)&g0[(size_t)n*GW + j4*4] = o;
        }
    }
}

// ---------------- gather + mean over 12 neighbors (f16) ----------------
__global__ __launch_bounds__(192) void gather_mean_kernel(const _Float16* __restrict__ g,
                                                          const int* __restrict__ idx,
                                                          _Float16* __restrict__ agg) {
    __shared__ int nb[KNN];
    const int n = blockIdx.x;
    if (threadIdx.x < KNN) nb[threadIdx.x] = idx[n*KNN + threadIdx.x];
    __syncthreads();
    float acc = 0.0f;
#pragma unroll
    for (int k = 0; k < KNN; ++k) acc += (float)g[(size_t)nb[k]*GW + threadIdx.x];
    agg[(size_t)n*GW + threadIdx.x] = (_Float16)(acc * (1.0f/12.0f));
}

// ---------------- FiLM params ----------------
__global__ __launch_bounds__(256) void film_kernel(const float* __restrict__ cond,
                                                   const float* __restrict__ Wf_g,
                                                   const float* __restrict__ bf_g,
                                                   const float* __restrict__ Wf_b,
                                                   const float* __restrict__ bf_b,
                                                   float* __restrict__ film) {
    const int l = blockIdx.x, j = threadIdx.x;
    float g = bf_g[l*WIDTH + j], b = bf_b[l*WIDTH + j];
    for (int c = 0; c < 64; ++c) {
        float cv = cond[c];
        g = fmaf(cv, Wf_g[(size_t)(l*64 + c)*WIDTH + j], g);
        b = fmaf(cv, Wf_b[(size_t)(l*64 + c)*WIDTH + j], b);
    }
    film[l*2*WIDTH + j]         = 1.0f + g;
    film[l*2*WIDTH + WIDTH + j] = b;
}

// ---------------- f16 MFMA GEMM: BM=128, BN=64, 4 waves ----------------
template<int EPI>
__global__ __launch_bounds__(256) void gemm_mfma(
    const _Float16* __restrict__ A1, const _Float16* __restrict__ A2,
    const _Float16* __restrict__ Bt, int K1, int Ktot, int NC,
    const float* __restrict__ bias, const float* __restrict__ film,
    const _Float16* __restrict__ h0, _Float16* __restrict__ C, int addSkip) {
    __shared__ _Float16 As[128*40];
    __shared__ _Float16 Bs[64*40];
    const int tid = threadIdx.x;
    const int bm = blockIdx.x * 128, bn = blockIdx.y * 64;
    const int wid = tid >> 6, lane = tid & 63;
    const int wm = (wid & 1) * 64, wn = (wid >> 1) * 32;
    const int m16 = lane & 15, kq = lane >> 4;
    const int ar = tid >> 1, ah = tid & 1;
    const int br = tid >> 2, bq = tid & 3;
    f4 acc[4][2];
#pragma unroll
    for (int i = 0; i < 4; ++i)
#pragma unroll
        for (int j = 0; j < 2; ++j) acc[i][j] = (f4){0.f, 0.f, 0.f, 0.f};

    for (int kc = 0; kc < Ktot; kc += 32) {
        const _Float16* Asrc; int kl, ldA;
        if (kc < K1) { Asrc = A1; kl = kc;      ldA = K1; }
        else         { Asrc = A2; kl = kc - K1; ldA = Ktot - K1; }
        {
            const float4* src = (const float4*)&Asrc[(size_t)(bm + ar)*ldA + kl + ah*16];
            *(float4*)&As[ar*40 + ah*16]     = src[0];
            *(float4*)&As[ar*40 + ah*16 + 8] = src[1];
        }
        *(float4*)&Bs[br*40 + bq*8] = *(const float4*)&Bt[(size_t)(bn + br)*Ktot + kc + bq*8];
        __syncthreads();
        half8 af[4], bf[2];
#pragma unroll
        for (int mt = 0; mt < 4; ++mt) af[mt] = *(half8*)&As[(wm + mt*16 + m16)*40 + kq*8];
#pragma unroll
        for (int nt = 0; nt < 2; ++nt) bf[nt] = *(half8*)&Bs[(wn + nt*16 + m16)*40 + kq*8];
#pragma unroll
        for (int mt = 0; mt < 4; ++mt)
#pragma unroll
            for (int nt = 0; nt < 2; ++nt)
                acc[mt][nt] = __builtin_amdgcn_mfma_f32_16x16x32_f16(af[mt], bf[nt], acc[mt][nt], 0, 0, 0);
        __syncthreads();
    }

#pragma unroll
    for (int mt = 0; mt < 4; ++mt) {
#pragma unroll
        for (int nt = 0; nt < 2; ++nt) {
            int col = bn + wn + nt*16 + m16;
#pragma unroll
            for (int r = 0; r < 4; ++r) {
                int row = bm + wm + mt*16 + kq*4 + r;
                float v = acc[mt][nt][r];
                if (EPI == 0) {
                    v = silu_f(v + bias[col]);
                } else if (EPI == 1) {
                    v = fmaf(v + bias[col], film[col], film[NC + col]);
                    v = silu_f(v);
                    if (addSkip) v += (float)h0[(size_t)row*NC + col];
                } else {
                    v += (float)h0[(size_t)row*NC + col];
                }
                C[(size_t)row*NC + col] = (_Float16)v;
            }
        }
    }
}

// ---------------- output head: (h @ W_out + b_out) * 0.01 ----------------
__global__ __launch_bounds__(256) void out_kernel(const _Float16* __restrict__ h,
                                                  const float* __restrict__ W_out,
                                                  const float* __restrict__ b_out,
                                                  float* __restrict__ out) {
    const int n = blockIdx.x * 256 + threadIdx.x;
    float a0 = 0.f, a1 = 0.f, a2 = 0.f;
#pragma unroll 4
    for (int k8 = 0; k8 < WIDTH/8; ++k8) {
        half8 v = *(const half8*)&h[(size_t)n*WIDTH + k8*8];
#pragma unroll
        for (int u = 0; u < 8; ++u) {
            float f = (float)v[u]; int k = k8*8 + u;
            a0 = fmaf(f, W_out[k*3+0], a0);
            a1 = fmaf(f, W_out[k*3+1], a1);
            a2 = fmaf(f, W_out[k*3+2], a2);
        }
    }
    out[n*3+0] = (a0 + b_out[0]) * 0.01f;
    out[n*3+1] = (a1 + b_out[1]) * 0.01f;
    out[n*3+2] = (a2 + b_out[2]) * 0.01f;
}

extern "C" void kernel_launch(void* const* d_in, const int* in_sizes, int n_in,
                              void* d_out, int out_size, void* d_ws, size_t ws_size,
                              hipStream_t stream) {
    const float* x      = (const float*)d_in[0];
    const float* cond   = (const float*)d_in[1];
    const float* Bf     = (const float*)d_in[2];
    const float* W_in   = (const float*)d_in[3];
    const float* b_in   = (const float*)d_in[4];
    const float* Wg_in  = (const float*)d_in[5];
    const float* bg_in  = (const float*)d_in[6];
    const float* Ws     = (const float*)d_in[7];
    const float* Wn     = (const float*)d_in[8];
    const float* bg     = (const float*)d_in[9];
    const float* Wg_out = (const float*)d_in[10];
    const float* W      = (const float*)d_in[11];
    const float* bmlp   = (const float*)d_in[12];
    const float* Wf_g   = (const float*)d_in[13];
    const float* bf_g   = (const float*)d_in[14];
    const float* Wf_b   = (const float*)d_in[15];
    const float* bf_b   = (const float*)d_in[16];
    const float* W_out  = (const float*)d_in[17];
    const float* b_out  = (const float*)d_in[18];
    float* out = (float*)d_out;

    char* ws = (char*)d_ws;
    int*       knn_idx = (int*)      (ws + 0);          //  3,145,728
    float4*    xw      = (float4*)   (ws + 3145728);    //  1,048,576
    float*     film    = (float*)    (ws + 4194304);    //     14,336
    _Float16*  Bg_t    = (_Float16*) (ws + 4210688);    //    589,824
    _Float16*  Wgo_t   = (_Float16*) (ws + 4800512);    //     98,304
    _Float16*  Wt      = (_Float16*) (ws + 4898816);    //    917,504
    _Float16*  h0      = (_Float16*) (ws + 5816320);    // 33,554,432 (f16) -> 39,370,752
    // kNN scratch overlays h0 (dead before fourier_input writes h0):
    int*       cnt     = (int*)      (ws + 5816320);    // 28,311,552 (192^3 SAT in place)
    float*     seed    = (float*)    (ws + 34127872);   //    262,144 -> 34,390,016
    float4*    xs      = (float4*)   (ws + 34390016);   //  1,048,576 -> 35,438,592
    int*       sidx    = (int*)      (ws + 35438592);   //    262,144 -> 35,700,736
    float4*    gbox    = (float4*)   (ws + 35700736);   //     32,768 -> 35,733,504
    int*       pcell   = (int*)      (ws + 35733504);   //    262,144 -> 35,995,648
    int*       prank   = (int*)      (ws + 35995648);   //    262,144 -> 36,257,792
    int*       cnt2    = (int*)      (ws + 36257792);   //  1,048,576 -> 37,306,368
    int*       start2  = (int*)      (ws + 37306368);   //  1,048,576 -> 38,354,944
    int*       sums    = (int*)      (ws + 38354944);   //      1,024 -> 38,355,968
    // pairs [seg][slot][gid] u16: SEGW*CAPS*NN*2 = 201,326,592 (overlays all
    // network activation buffers, dead during kNN; ws >= 256,114,688 per R1)
    unsigned short* pairs = (unsigned short*)(ws + 39370752);   // -> 240,697,344
    unsigned short* pcnt  = (unsigned short*)(ws + 240697344);  // 524,288 -> 241,221,632
    _Float16*  g_a     = (_Float16*) (ws + 39370752);   // 25,165,824
    _Float16*  g_b     = (_Float16*) (ws + 64536576);   // 25,165,824
    _Float16*  agg     = (_Float16*) (ws + 89702400);   // 25,165,824
    _Float16*  hA      = (_Float16*) (ws + 114868224);  // 33,554,432
    _Float16*  hB      = (_Float16*) (ws + 148422656);  // 33,554,432 -> 181,977,088

    // --- kNN: SAT seed -> 64^3 sort -> 4-wave-split ball scan -> exact top-12 ---
    prep_xw_kernel<<<NN/256, 256, 0, stream>>>(x, xw);
    zero_cnt_kernel<<<GC3/1024, 256, 0, stream>>>(cnt);
    hist_kernel<<<NN/256, 256, 0, stream>>>(xw, cnt);
    satx_kernel<<<GC*GC/256, 256, 0, stream>>>(cnt);
    saty_kernel<<<GC*GC/256, 256, 0, stream>>>(cnt);
    satz_kernel<<<GC*GC/256, 256, 0, stream>>>(cnt);
    seed_kernel<<<NN/256, 256, 0, stream>>>(xw, cnt, seed);
    zero_cnt_kernel<<<GC2_3/1024, 256, 0, stream>>>(cnt2);
    hist2_kernel<<<NN/256, 256, 0, stream>>>(xw, cnt2, pcell, prank);
    scan1_kernel<<<GC2_3/1024, 256, 0, stream>>>(cnt2, start2, sums);
    scan2_kernel<<<1, 256, 0, stream>>>(sums);
    scan3_kernel<<<GC2_3/256, 256, 0, stream>>>(start2, sums);
    scatter_kernel<<<NN/256, 256, 0, stream>>>(xw, pcell, prank, start2, xs, sidx);
    gbox_kernel<<<NG, 64, 0, stream>>>(xs, gbox);
    knn_ball_kernel<<<NN/64, 256, 0, stream>>>(xs, sidx, seed, gbox, pairs, pcnt);
    knn_topk_kernel<<<NN/256, 256, 0, stream>>>(xw, xs, sidx, pcnt, pairs, knn_idx);

    // --- network ---
    film_kernel<<<DEPTH, 256, 0, stream>>>(cond, Wf_g, bf_g, Wf_b, bf_b, film);
    convert_Wt_kernel<<<DEPTH*65536/256, 256, 0, stream>>>(W, Wt);
    convert_Bg_kernel<<<GLAYERS*73728/256, 256, 0, stream>>>(Ws, Wn, Bg_t);
    convert_Wgo_kernel<<<256*192/256, 256, 0, stream>>>(Wg_out, Wgo_t);
    fourier_input_kernel<<<NN/256, 256, 0, stream>>>(x, Bf, W_in, b_in, Wg_in, bg_in, h0, g_a);

    _Float16* gin = g_a; _Float16* gout = g_b;
    for (int l = 0; l < GLAYERS; ++l) {
        gather_mean_kernel<<<NN, GW, 0, stream>>>(gin, knn_idx, agg);
        gemm_mfma<0><<<dim3(NN/128, GW/64), 256, 0, stream>>>(
            gin, agg, Bg_t + (size_t)l*73728, GW, 2*GW, GW,
            bg + l*GW, nullptr, nullptr, gout, 0);
        _Float16* t = gin; gin = gout; gout = t;
    }
    // gin == g_a (4 swaps). inject: hA = h0 + gin @ Wg_out
    gemm_mfma<2><<<dim3(NN/128, WIDTH/64), 256, 0, stream>>>(
        gin, nullptr, Wgo_t, GW, GW, WIDTH, nullptr, nullptr, h0, hA, 0);

    _Float16* hin = hA; _Float16* hout = hB;
    for (int l = 0; l < DEPTH; ++l) {
        int skip = (l == 2 || l == 5) ? 1 : 0;   // SKIPS=(3,6): after layers idx 2,5
        gemm_mfma<1><<<dim3(NN/128, WIDTH/64), 256, 0, stream>>>(
            hin, nullptr, Wt + (size_t)l*65536, WIDTH, WIDTH, WIDTH,
            bmlp + l*WIDTH, film + l*2*WIDTH, h0, hout, skip);
        _Float16* t = hin; hin = hout; hout = t;
    }
    out_kernel<<<NN/256, 256, 0, stream>>>(hin, W_out, b_out, out);
}

// Round 14
// 2030.466 us; speedup vs baseline: 1.1264x; 1.1264x over previous
//
#include <hip/hip_runtime.h>
#include <math.h>

#define NN      65536
#define KNN     12
#define WIDTH   256
#define GW      192
#define DEPTH   7
#define GLAYERS 4
#define FF      48

#define QPT     8            // queries per thread in brute scan
#define KSEG    32           // candidate segments
#define SEGLEN  (NN/KSEG)    // 2048 candidates per segment
#define TILE    512          // LDS candidate tile (float4) = 8 KB
#define OCAP    384          // per-query overflow capacity (96 reg + 384 >= 384 max, R9)

// seed grid (SAT): 192^3 cells over [-6,6]^3, cell 0.0625
#define GC    192
#define GC3   7077888
#define GLO   (-6.0f)
#define GCW   0.0625f
#define GINV  16.0f

// sort grid: 64^3 cells for counting sort (groups of 64 sorted points)
#define GC2     64
#define GC2_3   262144
#define GINV2   5.3333333f
#define NG      1024          // NN/64 groups

typedef __attribute__((ext_vector_type(8))) _Float16 half8;
typedef __attribute__((ext_vector_type(4))) _Float16 half4;
typedef __attribute__((ext_vector_type(4))) float    f4;

__device__ __forceinline__ float silu_f(float v) { return v / (1.0f + expf(-v)); }

// top-12 ladders on NAMED scalars (SROA-safe)
#define KSWAP(A,B,IA,IB) do { if (B < A) { float _t=A; A=B; B=_t; int _u=IA; IA=IB; IB=_u; } } while(0)
#define KINSERT(DV,IV) do { b11=(DV); j11=(IV); \
    KSWAP(b10,b11,j10,j11); KSWAP(b9,b10,j9,j10); KSWAP(b8,b9,j8,j9); \
    KSWAP(b7,b8,j7,j8);  KSWAP(b6,b7,j6,j7);  KSWAP(b5,b6,j5,j6); \
    KSWAP(b4,b5,j4,j5);  KSWAP(b3,b4,j3,j4);  KSWAP(b2,b3,j2,j3); \
    KSWAP(b1,b2,j1,j2);  KSWAP(b0,b1,j0,j1); } while(0)
#define DSWAP(A,B) do { if (B < A) { float _t=A; A=B; B=_t; } } while(0)
#define DINSERT(DV) do { t11=(DV); \
    DSWAP(t10,t11); DSWAP(t9,t10); DSWAP(t8,t9); DSWAP(t7,t8); DSWAP(t6,t7); \
    DSWAP(t5,t6);  DSWAP(t4,t5);  DSWAP(t3,t4); DSWAP(t2,t3); DSWAP(t1,t2); DSWAP(t0,t1); } while(0)

// ---------------- prep: pack x + |x|^2 as float4 ----------------
__global__ __launch_bounds__(256) void prep_xw_kernel(const float* __restrict__ x,
                                                      float4* __restrict__ xw) {
    int i = blockIdx.x * 256 + threadIdx.x;
    float a = x[3*i], b = x[3*i+1], c = x[3*i+2];
    xw[i] = make_float4(a, b, c, a*a + b*b + c*c);
}

// ---------------- generic zero (int4 per thread) ----------------
__global__ __launch_bounds__(256) void zero_cnt_kernel(int* __restrict__ cnt) {
    int g = blockIdx.x*256 + threadIdx.x;
    *(int4*)&cnt[g*4] = make_int4(0,0,0,0);
}

__device__ __forceinline__ int cell_of(float v) {
    int c = (int)floorf((v - GLO) * GINV);
    return min(max(c, 0), GC-1);
}
__device__ __forceinline__ int cell2_of(float v) {
    int c = (int)floorf((v - GLO) * GINV2);
    return min(max(c, 0), GC2-1);
}

// ---------------- 192^3 hist + 3-pass in-place SAT + per-query seed bound ----------------
__global__ __launch_bounds__(256) void hist_kernel(const float4* __restrict__ xw,
                                                   int* __restrict__ cnt) {
    int i = blockIdx.x*256 + threadIdx.x;
    float4 p = xw[i];
    atomicAdd(&cnt[(cell_of(p.z)*GC + cell_of(p.y))*GC + cell_of(p.x)], 1);
}

__global__ __launch_bounds__(256) void satx_kernel(int* __restrict__ S) {
    int zy = blockIdx.x*256 + threadIdx.x;
    int base = zy * GC, run = 0;
    for (int i = 0; i < GC; ++i) { run += S[base+i]; S[base+i] = run; }
}
__global__ __launch_bounds__(256) void saty_kernel(int* __restrict__ S) {
    int t = blockIdx.x*256 + threadIdx.x;
    int z = t / GC, xx = t % GC, run = 0;
    for (int y = 0; y < GC; ++y) { int idx = (z*GC + y)*GC + xx; run += S[idx]; S[idx] = run; }
}
__global__ __launch_bounds__(256) void satz_kernel(int* __restrict__ S) {
    int t = blockIdx.x*256 + threadIdx.x;
    int y = t / GC, xx = t % GC, run = 0;
    for (int z = 0; z < GC; ++z) { int idx = (z*GC + y)*GC + xx; run += S[idx]; S[idx] = run; }
}

__device__ __forceinline__ int satv(const int* __restrict__ S, int xx, int y, int z) {
    if (xx < 0 || y < 0 || z < 0) return 0;
    return S[(z*GC + y)*GC + xx];
}

__global__ __launch_bounds__(256) void seed_kernel(const float4* __restrict__ xw,
                                                   const int* __restrict__ S,
                                                   float* __restrict__ seed) {
    int q = blockIdx.x*256 + threadIdx.x;
    float4 me = xw[q];
    int cx = cell_of(me.x), cy = cell_of(me.y), cz = cell_of(me.z);
    for (int R = 1; R < GC; ++R) {
        int x0 = max(cx-R, 0), x1 = min(cx+R, GC-1);
        int y0 = max(cy-R, 0), y1 = min(cy+R, GC-1);
        int z0 = max(cz-R, 0), z1 = min(cz+R, GC-1);
        int c = satv(S,x1,y1,z1) - satv(S,x0-1,y1,z1) - satv(S,x1,y0-1,z1) - satv(S,x1,y1,z0-1)
              + satv(S,x0-1,y0-1,z1) + satv(S,x0-1,y1,z0-1) + satv(S,x1,y0-1,z0-1)
              - satv(S,x0-1,y0-1,z0-1);
        if (c >= KNN + 1) {
            float dx = fmaxf(me.x - (GLO + x0*GCW), (GLO + (x1+1)*GCW) - me.x);
            float dy = fmaxf(me.y - (GLO + y0*GCW), (GLO + (y1+1)*GCW) - me.y);
            float dz = fmaxf(me.z - (GLO + z0*GCW), (GLO + (z1+1)*GCW) - me.z);
            seed[q] = (dx*dx + dy*dy + dz*dz) * 1.00002f + 1e-6f;
            return;
        }
    }
    seed[q] = 3e38f;
}

// ---------------- 64^3 counting sort: hist2, scan x3, scatter ----------------
__global__ __launch_bounds__(256) void hist2_kernel(const float4* __restrict__ xw,
                                                    int* __restrict__ cnt2,
                                                    int* __restrict__ pcell,
                                                    int* __restrict__ prank) {
    int i = blockIdx.x*256 + threadIdx.x;
    float4 p = xw[i];
    int c = (cell2_of(p.z)*GC2 + cell2_of(p.y))*GC2 + cell2_of(p.x);
    pcell[i] = c;
    prank[i] = atomicAdd(&cnt2[c], 1);
}

__global__ __launch_bounds__(256) void scan1_kernel(const int* __restrict__ cnt,
                                                    int* __restrict__ start,
                                                    int* __restrict__ sums) {
    __shared__ int lds[256];
    const int tid = threadIdx.x;
    int base = blockIdx.x*1024 + tid*4;
    int4 v = *(const int4*)&cnt[base];
    int s0 = v.x, s01 = v.x+v.y, s012 = s01+v.z, tot = s012+v.w;
    lds[tid] = tot; __syncthreads();
    for (int off = 1; off < 256; off <<= 1) {
        int t = (tid >= off) ? lds[tid-off] : 0;
        __syncthreads();
        lds[tid] += t;
        __syncthreads();
    }
    int excl = lds[tid] - tot;
    int4 o; o.x = excl; o.y = excl+s0; o.z = excl+s01; o.w = excl+s012;
    *(int4*)&start[base] = o;
    if (tid == 255) sums[blockIdx.x] = lds[255];
}

__global__ __launch_bounds__(256) void scan2_kernel(int* __restrict__ sums) {
    __shared__ int lds[256];
    const int tid = threadIdx.x;
    int v = sums[tid];
    lds[tid] = v; __syncthreads();
    for (int off = 1; off < 256; off <<= 1) {
        int t = (tid >= off) ? lds[tid-off] : 0;
        __syncthreads();
        lds[tid] += t;
        __syncthreads();
    }
    sums[tid] = lds[tid] - v;   // exclusive
}

__global__ __launch_bounds__(256) void scan3_kernel(int* __restrict__ start,
                                                    const int* __restrict__ sums) {
    int g = blockIdx.x*256 + threadIdx.x;
    start[g] += sums[g >> 10];
}

__global__ __launch_bounds__(256) void scatter_kernel(const float4* __restrict__ xw,
                                                      const int* __restrict__ pcell,
                                                      const int* __restrict__ prank,
                                                      const int* __restrict__ start,
                                                      float4* __restrict__ xs,
                                                      int* __restrict__ sidx) {
    int i = blockIdx.x*256 + threadIdx.x;
    int p = start[pcell[i]] + prank[i];
    xs[p] = xw[i];
    sidx[p] = i;
}

// ---------------- tighten: 12th-best dist among own group +-1 (valid upper bound) ----------------
// Lanes of a wave share a group -> candidate loads are wave-uniform (broadcast).
__global__ __launch_bounds__(256) void tighten_kernel(const float4* __restrict__ xs,
                                                      const int* __restrict__ sidx,
                                                      const float* __restrict__ seed,
                                                      float* __restrict__ seedT) {
    const int gid = blockIdx.x*256 + threadIdx.x;
    const float4 me = xs[gid];
    const int q = sidx[gid];
    const float qsq = me.w;
    const int g = gid >> 6;
    const int j0 = max(g-1, 0) * 64;
    const int j1 = min(g+2, NG) * 64;
    float t0=3e38f,t1=3e38f,t2=3e38f,t3=3e38f,t4=3e38f,t5=3e38f,
          t6=3e38f,t7=3e38f,t8=3e38f,t9=3e38f,t10=3e38f,t11=3e38f;
    for (int j = j0; j < j1; ++j) {
        if (j == gid) continue;                 // self excluded
        float4 c = xs[j];
        float dot = me.x*c.x + me.y*c.y + me.z*c.z;
        float d = fmaf(-2.0f, dot, qsq + c.w);  // ref formula
        d = fmaxf(d, 0.0f);
        if (d < t11) DINSERT(d);
    }
    // >=128 non-self candidates -> t11 always finite; margin matches seed's
    seedT[q] = fminf(seed[q], t11*1.00002f + 1e-6f);
}

// ---------------- kNN phase 1: QPT=8 brute scan, packed-u64 output ----------------
// accept iff me.c - 0.5*c.w > ht (same fp form as R9-R13 passing rounds, thr tightened).
// <=3 accepts per (q,seg) held in registers, emitted as ONE u64 at [seg][q]
// (fully coalesced, every line 100% covered -> kills R11's 206 MB RMW traffic).
// Overflow (rare) spills via per-query atomic to ovf[q][OCAP].
#define FORQ(OP) OP(0) OP(1) OP(2) OP(3) OP(4) OP(5) OP(6) OP(7)

__global__ __launch_bounds__(256) void knn_pairs_kernel(const float4* __restrict__ xw,
                                                        const float* __restrict__ seedT,
                                                        unsigned long long* __restrict__ packed,
                                                        unsigned short* __restrict__ ovf,
                                                        int* __restrict__ oc) {
    __shared__ float4 tile[TILE];
    const int tid = threadIdx.x;
    const int qb  = blockIdx.x * (256*QPT);   // 2048 queries per block
    const int seg = blockIdx.y;

#define DECLQ(u) float mex##u, mey##u, mez##u, ht##u; int cnt##u=0, p0##u=0, p1##u=0, p2##u=0;
    FORQ(DECLQ)
#undef DECLQ
#define LOADQ(u) { int qq = qb + u*256 + tid; float4 m = xw[qq]; \
    mex##u = m.x; mey##u = m.y; mez##u = m.z; \
    ht##u = -0.5f*(seedT[qq] - m.w + 1e-3f); }
    FORQ(LOADQ)
#undef LOADQ

    for (int t0 = seg*SEGLEN; t0 < (seg+1)*SEGLEN; t0 += TILE) {
        __syncthreads();
        tile[tid]       = xw[t0 + tid];
        tile[tid + 256] = xw[t0 + 256 + tid];
        __syncthreads();
#pragma unroll 2
        for (int j = 0; j < TILE; ++j) {
            float4 c = tile[j];                   // wave-uniform: 1 broadcast b128
            float nh = -0.5f * c.w;
            int jg = t0 + j;
#define DISTQ(u) { float s = fmaf(mex##u, c.x, fmaf(mey##u, c.y, fmaf(mez##u, c.z, nh))); \
        if (s > ht##u) { \
            if      (cnt##u == 0) p0##u = jg; \
            else if (cnt##u == 1) p1##u = jg; \
            else if (cnt##u == 2) p2##u = jg; \
            else { int qq = qb + u*256 + tid; int o = atomicAdd(&oc[qq], 1); \
                   if (o < OCAP) ovf[(size_t)qq*OCAP + o] = (unsigned short)jg; } \
            ++cnt##u; } }
            FORQ(DISTQ)
#undef DISTQ
        }
    }
#define STQ(u) { int qq = qb + u*256 + tid; int c3 = cnt##u < 3 ? cnt##u : 3; \
    packed[(size_t)seg*NN + qq] = (unsigned long long)c3 \
        | ((unsigned long long)(unsigned short)p0##u << 16) \
        | ((unsigned long long)(unsigned short)p1##u << 32) \
        | ((unsigned long long)(unsigned short)p2##u << 48); }
    FORQ(STQ)
#undef STQ
}

// ---------------- kNN phase 2: exact top-12 over packed + overflow ----------------
__global__ __launch_bounds__(256) void knn_topk_kernel(const float4* __restrict__ xw,
                                                       const unsigned long long* __restrict__ packed,
                                                       const unsigned short* __restrict__ ovf,
                                                       const int* __restrict__ oc,
                                                       int* __restrict__ knn_idx) {
    const int q = blockIdx.x * 256 + threadIdx.x;
    const float4 me = xw[q];
    const float qsq = me.w;
    float b0=3e38f,b1=3e38f,b2=3e38f,b3=3e38f,b4=3e38f,b5=3e38f,
          b6=3e38f,b7=3e38f,b8=3e38f,b9=3e38f,b10=3e38f,b11=3e38f;
    int   j0=-1,j1=-1,j2=-1,j3=-1,j4=-1,j5=-1,j6=-1,j7=-1,j8=-1,j9=-1,j10=-1,j11=-1;
#define KTEST(IDX) { int _i = (IDX); if (_i != q) { float4 cc = xw[_i]; \
    float dot = me.x*cc.x + me.y*cc.y + me.z*cc.z; \
    float d = fmaf(-2.0f, dot, qsq + cc.w);  /* EXACT ref formula */ \
    d = fmaxf(d, 0.0f); \
    if (d < b11) KINSERT(d, _i); } }
    for (int s = 0; s < KSEG; ++s) {
        unsigned long long v = packed[(size_t)s*NN + q];   // coalesced across lanes
        int c = (int)(v & 0xFFFFull);
        if (c > 0) KTEST((int)((v >> 16) & 0xFFFFull));
        if (c > 1) KTEST((int)((v >> 32) & 0xFFFFull));
        if (c > 2) KTEST((int)((v >> 48) & 0xFFFFull));
    }
    int no = oc[q]; if (no > OCAP) no = OCAP;
    for (int i = 0; i < no; ++i) KTEST((int)ovf[(size_t)q*OCAP + i]);
#undef KTEST
    knn_idx[q*KNN+0]=j0;  knn_idx[q*KNN+1]=j1;  knn_idx[q*KNN+2]=j2;
    knn_idx[q*KNN+3]=j3;  knn_idx[q*KNN+4]=j4;  knn_idx[q*KNN+5]=j5;
    knn_idx[q*KNN+6]=j6;  knn_idx[q*KNN+7]=j7;  knn_idx[q*KNN+8]=j8;
    knn_idx[q*KNN+9]=j9;  knn_idx[q*KNN+10]=j10; knn_idx[q*KNN+11]=j11;
}

// ---------------- weight convert+transpose to f16 [N][K] ----------------
__global__ __launch_bounds__(256) void convert_Wt_kernel(const float* __restrict__ W,
                                                         _Float16* __restrict__ Wt) {
    int e = blockIdx.x*256 + threadIdx.x;
    int l = e >> 16, r = e & 65535;
    int n = r >> 8, k = r & 255;
    Wt[(size_t)l*65536 + n*256 + k] = (_Float16)W[(size_t)l*65536 + k*256 + n];
}

__global__ __launch_bounds__(256) void convert_Bg_kernel(const float* __restrict__ Ws,
                                                         const float* __restrict__ Wn,
                                                         _Float16* __restrict__ Bg) {
    int e = blockIdx.x*256 + threadIdx.x;
    int l = e / 73728, r = e % 73728;
    int n = r / 384, k = r % 384;
    float v = (k < 192) ? Ws[(size_t)l*36864 + k*192 + n]
                        : Wn[(size_t)l*36864 + (k-192)*192 + n];
    Bg[(size_t)l*73728 + (size_t)n*384 + k] = (_Float16)v;
}

__global__ __launch_bounds__(256) void convert_Wgo_kernel(const float* __restrict__ Wg_out,
                                                          _Float16* __restrict__ Wgo) {
    int e = blockIdx.x*256 + threadIdx.x;
    int n = e / 192, k = e % 192;
    Wgo[e] = (_Float16)Wg_out[k*256 + n];
}

// ---------------- fourier features + both input layers (f16 out) ----------------
__global__ __launch_bounds__(256) void fourier_input_kernel(
    const float* __restrict__ x, const float* __restrict__ Bf,
    const float* __restrict__ W_in, const float* __restrict__ b_in,
    const float* __restrict__ Wg_in, const float* __restrict__ bg_in,
    _Float16* __restrict__ h0, _Float16* __restrict__ g0) {
    const int n = blockIdx.x * 256 + threadIdx.x;
    const float x0 = x[3*n], x1 = x[3*n+1], x2 = x[3*n+2];
    float ff[FF];
#pragma unroll
    for (int sm = 0; sm < 24; ++sm) {
        int s = sm >> 3, m = sm & 7;
        float p = x0*Bf[s*24 + m] + x1*Bf[s*24 + 8 + m] + x2*Bf[s*24 + 16 + m];
        float sv, cv; sincosf(p, &sv, &cv);
        ff[sm] = sv; ff[24 + sm] = cv;
    }
    {
        const float4* W4 = (const float4*)W_in;
        const float4* b4 = (const float4*)b_in;
#pragma unroll 2
        for (int j4 = 0; j4 < WIDTH/4; ++j4) {
            float4 acc = b4[j4];
#pragma unroll
            for (int k = 0; k < FF; ++k) {
                float4 w = W4[k*(WIDTH/4) + j4]; float f = ff[k];
                acc.x = fmaf(f, w.x, acc.x); acc.y = fmaf(f, w.y, acc.y);
                acc.z = fmaf(f, w.z, acc.z); acc.w = fmaf(f, w.w, acc.w);
            }
            half4 o;
            o[0] = (_Float16)silu_f(acc.x); o[1] = (_Float16)silu_f(acc.y);
            o[2] = (_Float16)silu_f(acc.z); o[3] = (_Float16)silu_f(acc.w);
            *(half4*)&h0[(size_t)n*WIDTH + j4*4] = o;
        }
    }
    {
        const float4* W4 = (const float4*)Wg_in;
        const float4* b4 = (const float4*)bg_in;
#pragma unroll 2
        for (int j4 = 0; j4 < GW/4; ++j4) {
            float4 acc = b4[j4];
#pragma unroll
            for (int k = 0; k < FF; ++k) {
                float4 w = W4[k*(GW/4) + j4]; float f = ff[k];
                acc.x = fmaf(f, w.x, acc.x); acc.y = fmaf(f, w.y, acc.y);
                acc.z = fmaf(f, w.z, acc.z); acc.w = fmaf(f, w.w, acc.w);
            }
            half4 o;
            o[0] = (_Float16)silu_f(acc.x); o[1] = (_Float16)silu_f(acc.y);
            o[2] = (_Float16)silu_f(acc.z); o[3] = (_Float16)silu_f(acc.w);
            *(half4*)&g0[(size_t)n*GW + j4*4] = o;
        }
    }
}

// ---------------- gather + mean over 12 neighbors (f16) ----------------
__global__ __launch_bounds__(192) void gather_mean_kernel(const _Float16* __restrict__ g,
                                                          const int* __restrict__ idx,
                                                          _Float16* __restrict__ agg) {
    __shared__ int nb[KNN];
    const int n = blockIdx.x;
    if (threadIdx.x < KNN) nb[threadIdx.x] = idx[n*KNN + threadIdx.x];
    __syncthreads();
    float acc = 0.0f;
#pragma unroll
    for (int k = 0; k < KNN; ++k) acc += (float)g[(size_t)nb[k]*GW + threadIdx.x];
    agg[(size_t)n*GW + threadIdx.x] = (_Float16)(acc * (1.0f/12.0f));
}

// ---------------- FiLM params ----------------
__global__ __launch_bounds__(256) void film_kernel(const float* __restrict__ cond,
                                                   const float* __restrict__ Wf_g,
                                                   const float* __restrict__ bf_g,
                                                   const float* __restrict__ Wf_b,
                                                   const float* __restrict__ bf_b,
                                                   float* __restrict__ film) {
    const int l = blockIdx.x, j = threadIdx.x;
    float g = bf_g[l*WIDTH + j], b = bf_b[l*WIDTH + j];
    for (int c = 0; c < 64; ++c) {
        float cv = cond[c];
        g = fmaf(cv, Wf_g[(size_t)(l*64 + c)*WIDTH + j], g);
        b = fmaf(cv, Wf_b[(size_t)(l*64 + c)*WIDTH + j], b);
    }
    film[l*2*WIDTH + j]         = 1.0f + g;
    film[l*2*WIDTH + WIDTH + j] = b;
}

// ---------------- f16 MFMA GEMM: BM=128, BN=64, 4 waves ----------------
template<int EPI>
__global__ __launch_bounds__(256) void gemm_mfma(
    const _Float16* __restrict__ A1, const _Float16* __restrict__ A2,
    const _Float16* __restrict__ Bt, int K1, int Ktot, int NC,
    const float* __restrict__ bias, const float* __restrict__ film,
    const _Float16* __restrict__ h0, _Float16* __restrict__ C, int addSkip) {
    __shared__ _Float16 As[128*40];
    __shared__ _Float16 Bs[64*40];
    const int tid = threadIdx.x;
    const int bm = blockIdx.x * 128, bn = blockIdx.y * 64;
    const int wid = tid >> 6, lane = tid & 63;
    const int wm = (wid & 1) * 64, wn = (wid >> 1) * 32;
    const int m16 = lane & 15, kq = lane >> 4;
    const int ar = tid >> 1, ah = tid & 1;
    const int br = tid >> 2, bq = tid & 3;
    f4 acc[4][2];
#pragma unroll
    for (int i = 0; i < 4; ++i)
#pragma unroll
        for (int j = 0; j < 2; ++j) acc[i][j] = (f4){0.f, 0.f, 0.f, 0.f};

    for (int kc = 0; kc < Ktot; kc += 32) {
        const _Float16* Asrc; int kl, ldA;
        if (kc < K1) { Asrc = A1; kl = kc;      ldA = K1; }
        else         { Asrc = A2; kl = kc - K1; ldA = Ktot - K1; }
        {
            const float4* src = (const float4*)&Asrc[(size_t)(bm + ar)*ldA + kl + ah*16];
            *(float4*)&As[ar*40 + ah*16]     = src[0];
            *(float4*)&As[ar*40 + ah*16 + 8] = src[1];
        }
        *(float4*)&Bs[br*40 + bq*8] = *(const float4*)&Bt[(size_t)(bn + br)*Ktot + kc + bq*8];
        __syncthreads();
        half8 af[4], bf[2];
#pragma unroll
        for (int mt = 0; mt < 4; ++mt) af[mt] = *(half8*)&As[(wm + mt*16 + m16)*40 + kq*8];
#pragma unroll
        for (int nt = 0; nt < 2; ++nt) bf[nt] = *(half8*)&Bs[(wn + nt*16 + m16)*40 + kq*8];
#pragma unroll
        for (int mt = 0; mt < 4; ++mt)
#pragma unroll
            for (int nt = 0; nt < 2; ++nt)
                acc[mt][nt] = __builtin_amdgcn_mfma_f32_16x16x32_f16(af[mt], bf[nt], acc[mt][nt], 0, 0, 0);
        __syncthreads();
    }

#pragma unroll
    for (int mt = 0; mt < 4; ++mt) {
#pragma unroll
        for (int nt = 0; nt < 2; ++nt) {
            int col = bn + wn + nt*16 + m16;
#pragma unroll
            for (int r = 0; r < 4; ++r) {
                int row = bm + wm + mt*16 + kq*4 + r;
                float v = acc[mt][nt][r];
                if (EPI == 0) {
                    v = silu_f(v + bias[col]);
                } else if (EPI == 1) {
                    v = fmaf(v + bias[col], film[col], film[NC + col]);
                    v = silu_f(v);
                    if (addSkip) v += (float)h0[(size_t)row*NC + col];
                } else {
                    v += (float)h0[(size_t)row*NC + col];
                }
                C[(size_t)row*NC + col] = (_Float16)v;
            }
        }
    }
}

// ---------------- output head: (h @ W_out + b_out) * 0.01 ----------------
__global__ __launch_bounds__(256) void out_kernel(const _Float16* __restrict__ h,
                                                  const float* __restrict__ W_out,
                                                  const float* __restrict__ b_out,
                                                  float* __restrict__ out) {
    const int n = blockIdx.x * 256 + threadIdx.x;
    float a0 = 0.f, a1 = 0.f, a2 = 0.f;
#pragma unroll 4
    for (int k8 = 0; k8 < WIDTH/8; ++k8) {
        half8 v = *(const half8*)&h[(size_t)n*WIDTH + k8*8];
#pragma unroll
        for (int u = 0; u < 8; ++u) {
            float f = (float)v[u]; int k = k8*8 + u;
            a0 = fmaf(f, W_out[k*3+0], a0);
            a1 = fmaf(f, W_out[k*3+1], a1);
            a2 = fmaf(f, W_out[k*3+2], a2);
        }
    }
    out[n*3+0] = (a0 + b_out[0]) * 0.01f;
    out[n*3+1] = (a1 + b_out[1]) * 0.01f;
    out[n*3+2] = (a2 + b_out[2]) * 0.01f;
}

extern "C" void kernel_launch(void* const* d_in, const int* in_sizes, int n_in,
                              void* d_out, int out_size, void* d_ws, size_t ws_size,
                              hipStream_t stream) {
    const float* x      = (const float*)d_in[0];
    const float* cond   = (const float*)d_in[1];
    const float* Bf     = (const float*)d_in[2];
    const float* W_in   = (const float*)d_in[3];
    const float* b_in   = (const float*)d_in[4];
    const float* Wg_in  = (const float*)d_in[5];
    const float* bg_in  = (const float*)d_in[6];
    const float* Ws     = (const float*)d_in[7];
    const float* Wn     = (const float*)d_in[8];
    const float* bg     = (const float*)d_in[9];
    const float* Wg_out = (const float*)d_in[10];
    const float* W      = (const float*)d_in[11];
    const float* bmlp   = (const float*)d_in[12];
    const float* Wf_g   = (const float*)d_in[13];
    const float* bf_g   = (const float*)d_in[14];
    const float* Wf_b   = (const float*)d_in[15];
    const float* bf_b   = (const float*)d_in[16];
    const float* W_out  = (const float*)d_in[17];
    const float* b_out  = (const float*)d_in[18];
    float* out = (float*)d_out;

    char* ws = (char*)d_ws;
    int*       knn_idx = (int*)      (ws + 0);          //  3,145,728
    float4*    xw      = (float4*)   (ws + 3145728);    //  1,048,576
    float*     film    = (float*)    (ws + 4194304);    //     14,336
    _Float16*  Bg_t    = (_Float16*) (ws + 4210688);    //    589,824
    _Float16*  Wgo_t   = (_Float16*) (ws + 4800512);    //     98,304
    _Float16*  Wt      = (_Float16*) (ws + 4898816);    //    917,504
    _Float16*  h0      = (_Float16*) (ws + 5816320);    // 33,554,432 (f16) -> 39,370,752
    // kNN scratch overlays h0 (dead before fourier_input writes h0):
    int*       cnt     = (int*)      (ws + 5816320);    // 28,311,552 (192^3 SAT in place)
    float*     seed    = (float*)    (ws + 34127872);   //    262,144 -> 34,390,016
    float4*    xs      = (float4*)   (ws + 34390016);   //  1,048,576 -> 35,438,592
    int*       sidx    = (int*)      (ws + 35438592);   //    262,144 -> 35,700,736
    int*       pcell   = (int*)      (ws + 35700736);   //    262,144 -> 35,962,880
    int*       prank   = (int*)      (ws + 35962880);   //    262,144 -> 36,225,024
    int*       cnt2    = (int*)      (ws + 36225024);   //  1,048,576 -> 37,273,600
    int*       start2  = (int*)      (ws + 37273600);   //  1,048,576 -> 38,322,176
    int*       sums    = (int*)      (ws + 38322176);   //      1,024 -> 38,323,200
    float*     seedT   = (float*)    (ws + 38323200);   //    262,144 -> 38,585,344 < h0 end
    // packed/ovf/oc overlay g_a..agg region (dead during kNN):
    unsigned long long* packed = (unsigned long long*)(ws + 39370752);   // 16,777,216 -> 56,147,968
    unsigned short*     ovf    = (unsigned short*)    (ws + 56147968);   // 50,331,648 -> 106,479,616
    int*                oc     = (int*)               (ws + 106479616);  //    262,144 -> 106,741,760
    _Float16*  g_a     = (_Float16*) (ws + 39370752);   // 25,165,824
    _Float16*  g_b     = (_Float16*) (ws + 64536576);   // 25,165,824
    _Float16*  agg     = (_Float16*) (ws + 89702400);   // 25,165,824
    _Float16*  hA      = (_Float16*) (ws + 114868224);  // 33,554,432
    _Float16*  hB      = (_Float16*) (ws + 148422656);  // 33,554,432 -> 181,977,088

    // --- kNN: SAT seed -> sort -> tighten -> packed brute scan -> exact top-12 ---
    prep_xw_kernel<<<NN/256, 256, 0, stream>>>(x, xw);
    zero_cnt_kernel<<<GC3/1024, 256, 0, stream>>>(cnt);
    hist_kernel<<<NN/256, 256, 0, stream>>>(xw, cnt);
    satx_kernel<<<GC*GC/256, 256, 0, stream>>>(cnt);
    saty_kernel<<<GC*GC/256, 256, 0, stream>>>(cnt);
    satz_kernel<<<GC*GC/256, 256, 0, stream>>>(cnt);
    seed_kernel<<<NN/256, 256, 0, stream>>>(xw, cnt, seed);
    zero_cnt_kernel<<<GC2_3/1024, 256, 0, stream>>>(cnt2);
    hist2_kernel<<<NN/256, 256, 0, stream>>>(xw, cnt2, pcell, prank);
    scan1_kernel<<<GC2_3/1024, 256, 0, stream>>>(cnt2, start2, sums);
    scan2_kernel<<<1, 256, 0, stream>>>(sums);
    scan3_kernel<<<GC2_3/256, 256, 0, stream>>>(start2, sums);
    scatter_kernel<<<NN/256, 256, 0, stream>>>(xw, pcell, prank, start2, xs, sidx);
    tighten_kernel<<<NN/256, 256, 0, stream>>>(xs, sidx, seed, seedT);
    zero_cnt_kernel<<<NN/1024, 256, 0, stream>>>(oc);     // FULL oc zero (R8 lesson)
    knn_pairs_kernel<<<dim3(NN/(256*QPT), KSEG), 256, 0, stream>>>(xw, seedT, packed, ovf, oc);
    knn_topk_kernel<<<NN/256, 256, 0, stream>>>(xw, packed, ovf, oc, knn_idx);

    // --- network ---
    film_kernel<<<DEPTH, 256, 0, stream>>>(cond, Wf_g, bf_g, Wf_b, bf_b, film);
    convert_Wt_kernel<<<DEPTH*65536/256, 256, 0, stream>>>(W, Wt);
    convert_Bg_kernel<<<GLAYERS*73728/256, 256, 0, stream>>>(Ws, Wn, Bg_t);
    convert_Wgo_kernel<<<256*192/256, 256, 0, stream>>>(Wg_out, Wgo_t);
    fourier_input_kernel<<<NN/256, 256, 0, stream>>>(x, Bf, W_in, b_in, Wg_in, bg_in, h0, g_a);

    _Float16* gin = g_a; _Float16* gout = g_b;
    for (int l = 0; l < GLAYERS; ++l) {
        gather_mean_kernel<<<NN, GW, 0, stream>>>(gin, knn_idx, agg);
        gemm_mfma<0><<<dim3(NN/128, GW/64), 256, 0, stream>>>(
            gin, agg, Bg_t + (size_t)l*73728, GW, 2*GW, GW,
            bg + l*GW, nullptr, nullptr, gout, 0);
        _Float16* t = gin; gin = gout; gout = t;
    }
    // gin == g_a (4 swaps). inject: hA = h0 + gin @ Wg_out
    gemm_mfma<2><<<dim3(NN/128, WIDTH/64), 256, 0, stream>>>(
        gin, nullptr, Wgo_t, GW, GW, WIDTH, nullptr, nullptr, h0, hA, 0);

    _Float16* hin = hA; _Float16* hout = hB;
    for (int l = 0; l < DEPTH; ++l) {
        int skip = (l == 2 || l == 5) ? 1 : 0;   // SKIPS=(3,6): after layers idx 2,5
        gemm_mfma<1><<<dim3(NN/128, WIDTH/64), 256, 0, stream>>>(
            hin, nullptr, Wt + (size_t)l*65536, WIDTH, WIDTH, WIDTH,
            bmlp + l*WIDTH, film + l*2*WIDTH, h0, hout, skip);
        _Float16* t = hin; hin = hout; hout = t;
    }
    out_kernel<<<NN/256, 256, 0, stream>>>(hin, W_out, b_out, out);
}

// Round 15
// 1920.006 us; speedup vs baseline: 1.1912x; 1.0575x over previous
//
#include <hip/hip_runtime.h>
#include <math.h>

#define NN      65536
#define KNN     12
#define WIDTH   256
#define GW      192
#define DEPTH   7
#define GLAYERS 4
#define FF      48

#define QPT     8            // queries per thread in brute scan
#define KSEG    32           // candidate segments
#define SEGLEN  (NN/KSEG)    // 2048 candidates per segment
#define TILE    512          // LDS candidate tile (float4) = 8 KB
#define OCAP    384          // per-query overflow capacity

// seed grid (SAT): 192^3 cells over [-6,6]^3, cell 0.0625
#define GC    192
#define GC3   7077888
#define GLO   (-6.0f)
#define GCW   0.0625f
#define GINV  16.0f

// sort grid: 64^3 cells for counting sort
#define GC2     64
#define GC2_3   262144
#define GINV2   5.3333333f
#define NG      1024          // NN/64 groups

typedef __attribute__((ext_vector_type(8))) _Float16 half8;
typedef __attribute__((ext_vector_type(4))) _Float16 half4;
typedef __attribute__((ext_vector_type(4))) float    f4;

__device__ __forceinline__ float silu_f(float v) { return v / (1.0f + expf(-v)); }

// top-12 ladders on NAMED scalars (SROA-safe)
#define KSWAP(A,B,IA,IB) do { if (B < A) { float _t=A; A=B; B=_t; int _u=IA; IA=IB; IB=_u; } } while(0)
#define KINSERT(DV,IV) do { b11=(DV); j11=(IV); \
    KSWAP(b10,b11,j10,j11); KSWAP(b9,b10,j9,j10); KSWAP(b8,b9,j8,j9); \
    KSWAP(b7,b8,j7,j8);  KSWAP(b6,b7,j6,j7);  KSWAP(b5,b6,j5,j6); \
    KSWAP(b4,b5,j4,j5);  KSWAP(b3,b4,j3,j4);  KSWAP(b2,b3,j2,j3); \
    KSWAP(b1,b2,j1,j2);  KSWAP(b0,b1,j0,j1); } while(0)
#define DSWAP(A,B) do { if (B < A) { float _t=A; A=B; B=_t; } } while(0)
#define DINSERT(DV) do { t11=(DV); \
    DSWAP(t10,t11); DSWAP(t9,t10); DSWAP(t8,t9); DSWAP(t7,t8); DSWAP(t6,t7); \
    DSWAP(t5,t6);  DSWAP(t4,t5);  DSWAP(t3,t4); DSWAP(t2,t3); DSWAP(t1,t2); DSWAP(t0,t1); } while(0)

// ---------------- prep: pack x + |x|^2 as float4 ----------------
__global__ __launch_bounds__(256) void prep_xw_kernel(const float* __restrict__ x,
                                                      float4* __restrict__ xw) {
    int i = blockIdx.x * 256 + threadIdx.x;
    float a = x[3*i], b = x[3*i+1], c = x[3*i+2];
    xw[i] = make_float4(a, b, c, a*a + b*b + c*c);
}

// ---------------- generic zero (int4 per thread) ----------------
__global__ __launch_bounds__(256) void zero_cnt_kernel(int* __restrict__ cnt) {
    int g = blockIdx.x*256 + threadIdx.x;
    *(int4*)&cnt[g*4] = make_int4(0,0,0,0);
}

__device__ __forceinline__ int cell_of(float v) {
    int c = (int)floorf((v - GLO) * GINV);
    return min(max(c, 0), GC-1);
}
__device__ __forceinline__ int cell2_of(float v) {
    int c = (int)floorf((v - GLO) * GINV2);
    return min(max(c, 0), GC2-1);
}

// ---------------- 192^3 hist + 3-pass in-place SAT + per-query seed bound ----------------
__global__ __launch_bounds__(256) void hist_kernel(const float4* __restrict__ xw,
                                                   int* __restrict__ cnt) {
    int i = blockIdx.x*256 + threadIdx.x;
    float4 p = xw[i];
    atomicAdd(&cnt[(cell_of(p.z)*GC + cell_of(p.y))*GC + cell_of(p.x)], 1);
}

__global__ __launch_bounds__(256) void satx_kernel(int* __restrict__ S) {
    int zy = blockIdx.x*256 + threadIdx.x;
    int base = zy * GC, run = 0;
    for (int i = 0; i < GC; ++i) { run += S[base+i]; S[base+i] = run; }
}
__global__ __launch_bounds__(256) void saty_kernel(int* __restrict__ S) {
    int t = blockIdx.x*256 + threadIdx.x;
    int z = t / GC, xx = t % GC, run = 0;
    for (int y = 0; y < GC; ++y) { int idx = (z*GC + y)*GC + xx; run += S[idx]; S[idx] = run; }
}
__global__ __launch_bounds__(256) void satz_kernel(int* __restrict__ S) {
    int t = blockIdx.x*256 + threadIdx.x;
    int y = t / GC, xx = t % GC, run = 0;
    for (int z = 0; z < GC; ++z) { int idx = (z*GC + y)*GC + xx; run += S[idx]; S[idx] = run; }
}

__device__ __forceinline__ int satv(const int* __restrict__ S, int xx, int y, int z) {
    if (xx < 0 || y < 0 || z < 0) return 0;
    return S[(z*GC + y)*GC + xx];
}

__global__ __launch_bounds__(256) void seed_kernel(const float4* __restrict__ xw,
                                                   const int* __restrict__ S,
                                                   float* __restrict__ seed) {
    int q = blockIdx.x*256 + threadIdx.x;
    float4 me = xw[q];
    int cx = cell_of(me.x), cy = cell_of(me.y), cz = cell_of(me.z);
    for (int R = 1; R < GC; ++R) {
        int x0 = max(cx-R, 0), x1 = min(cx+R, GC-1);
        int y0 = max(cy-R, 0), y1 = min(cy+R, GC-1);
        int z0 = max(cz-R, 0), z1 = min(cz+R, GC-1);
        int c = satv(S,x1,y1,z1) - satv(S,x0-1,y1,z1) - satv(S,x1,y0-1,z1) - satv(S,x1,y1,z0-1)
              + satv(S,x0-1,y0-1,z1) + satv(S,x0-1,y1,z0-1) + satv(S,x1,y0-1,z0-1)
              - satv(S,x0-1,y0-1,z0-1);
        if (c >= KNN + 1) {
            float dx = fmaxf(me.x - (GLO + x0*GCW), (GLO + (x1+1)*GCW) - me.x);
            float dy = fmaxf(me.y - (GLO + y0*GCW), (GLO + (y1+1)*GCW) - me.y);
            float dz = fmaxf(me.z - (GLO + z0*GCW), (GLO + (z1+1)*GCW) - me.z);
            seed[q] = (dx*dx + dy*dy + dz*dz) * 1.00002f + 1e-6f;
            return;
        }
    }
    seed[q] = 3e38f;
}

// ---------------- 64^3 counting sort: hist2, scan x3, scatter (+inverse perm) ----------------
__global__ __launch_bounds__(256) void hist2_kernel(const float4* __restrict__ xw,
                                                    int* __restrict__ cnt2,
                                                    int* __restrict__ pcell,
                                                    int* __restrict__ prank) {
    int i = blockIdx.x*256 + threadIdx.x;
    float4 p = xw[i];
    int c = (cell2_of(p.z)*GC2 + cell2_of(p.y))*GC2 + cell2_of(p.x);
    pcell[i] = c;
    prank[i] = atomicAdd(&cnt2[c], 1);
}

__global__ __launch_bounds__(256) void scan1_kernel(const int* __restrict__ cnt,
                                                    int* __restrict__ start,
                                                    int* __restrict__ sums) {
    __shared__ int lds[256];
    const int tid = threadIdx.x;
    int base = blockIdx.x*1024 + tid*4;
    int4 v = *(const int4*)&cnt[base];
    int s0 = v.x, s01 = v.x+v.y, s012 = s01+v.z, tot = s012+v.w;
    lds[tid] = tot; __syncthreads();
    for (int off = 1; off < 256; off <<= 1) {
        int t = (tid >= off) ? lds[tid-off] : 0;
        __syncthreads();
        lds[tid] += t;
        __syncthreads();
    }
    int excl = lds[tid] - tot;
    int4 o; o.x = excl; o.y = excl+s0; o.z = excl+s01; o.w = excl+s012;
    *(int4*)&start[base] = o;
    if (tid == 255) sums[blockIdx.x] = lds[255];
}

__global__ __launch_bounds__(256) void scan2_kernel(int* __restrict__ sums) {
    __shared__ int lds[256];
    const int tid = threadIdx.x;
    int v = sums[tid];
    lds[tid] = v; __syncthreads();
    for (int off = 1; off < 256; off <<= 1) {
        int t = (tid >= off) ? lds[tid-off] : 0;
        __syncthreads();
        lds[tid] += t;
        __syncthreads();
    }
    sums[tid] = lds[tid] - v;   // exclusive
}

__global__ __launch_bounds__(256) void scan3_kernel(int* __restrict__ start,
                                                    const int* __restrict__ sums) {
    int g = blockIdx.x*256 + threadIdx.x;
    start[g] += sums[g >> 10];
}

__global__ __launch_bounds__(256) void scatter_kernel(const float4* __restrict__ xw,
                                                      const int* __restrict__ pcell,
                                                      const int* __restrict__ prank,
                                                      const int* __restrict__ start,
                                                      float4* __restrict__ xs,
                                                      int* __restrict__ sidx,
                                                      int* __restrict__ inv) {
    int i = blockIdx.x*256 + threadIdx.x;
    int p = start[pcell[i]] + prank[i];
    xs[p] = xw[i];
    sidx[p] = i;
    inv[i] = p;
}

// ---------------- tighten: 12th-best dist among own group +-1 (valid upper bound) ----------------
__global__ __launch_bounds__(256) void tighten_kernel(const float4* __restrict__ xs,
                                                      const int* __restrict__ sidx,
                                                      const float* __restrict__ seed,
                                                      float* __restrict__ seedT) {
    const int gid = blockIdx.x*256 + threadIdx.x;
    const float4 me = xs[gid];
    const int q = sidx[gid];
    const float qsq = me.w;
    const int g = gid >> 6;
    const int j0 = max(g-1, 0) * 64;
    const int j1 = min(g+2, NG) * 64;
    float t0=3e38f,t1=3e38f,t2=3e38f,t3=3e38f,t4=3e38f,t5=3e38f,
          t6=3e38f,t7=3e38f,t8=3e38f,t9=3e38f,t10=3e38f,t11=3e38f;
    for (int j = j0; j < j1; ++j) {
        if (j == gid) continue;
        float4 c = xs[j];
        float dot = me.x*c.x + me.y*c.y + me.z*c.z;
        float d = fmaf(-2.0f, dot, qsq + c.w);
        d = fmaxf(d, 0.0f);
        if (d < t11) DINSERT(d);
    }
    seedT[q] = fminf(seed[q], t11*1.00002f + 1e-6f);
}

// ---------------- kNN phase 1: QPT=8 brute scan, packed-u64 output ----------------
#define FORQ(OP) OP(0) OP(1) OP(2) OP(3) OP(4) OP(5) OP(6) OP(7)

__global__ __launch_bounds__(256) void knn_pairs_kernel(const float4* __restrict__ xw,
                                                        const float* __restrict__ seedT,
                                                        unsigned long long* __restrict__ packed,
                                                        unsigned short* __restrict__ ovf,
                                                        int* __restrict__ oc) {
    __shared__ float4 tile[TILE];
    const int tid = threadIdx.x;
    const int qb  = blockIdx.x * (256*QPT);
    const int seg = blockIdx.y;

#define DECLQ(u) float mex##u, mey##u, mez##u, ht##u; int cnt##u=0, p0##u=0, p1##u=0, p2##u=0;
    FORQ(DECLQ)
#undef DECLQ
#define LOADQ(u) { int qq = qb + u*256 + tid; float4 m = xw[qq]; \
    mex##u = m.x; mey##u = m.y; mez##u = m.z; \
    ht##u = -0.5f*(seedT[qq] - m.w + 1e-3f); }
    FORQ(LOADQ)
#undef LOADQ

    for (int t0 = seg*SEGLEN; t0 < (seg+1)*SEGLEN; t0 += TILE) {
        __syncthreads();
        tile[tid]       = xw[t0 + tid];
        tile[tid + 256] = xw[t0 + 256 + tid];
        __syncthreads();
#pragma unroll 2
        for (int j = 0; j < TILE; ++j) {
            float4 c = tile[j];
            float nh = -0.5f * c.w;
            int jg = t0 + j;
#define DISTQ(u) { float s = fmaf(mex##u, c.x, fmaf(mey##u, c.y, fmaf(mez##u, c.z, nh))); \
        if (s > ht##u) { \
            if      (cnt##u == 0) p0##u = jg; \
            else if (cnt##u == 1) p1##u = jg; \
            else if (cnt##u == 2) p2##u = jg; \
            else { int qq = qb + u*256 + tid; int o = atomicAdd(&oc[qq], 1); \
                   if (o < OCAP) ovf[(size_t)qq*OCAP + o] = (unsigned short)jg; } \
            ++cnt##u; } }
            FORQ(DISTQ)
#undef DISTQ
        }
    }
#define STQ(u) { int qq = qb + u*256 + tid; int c3 = cnt##u < 3 ? cnt##u : 3; \
    packed[(size_t)seg*NN + qq] = (unsigned long long)c3 \
        | ((unsigned long long)(unsigned short)p0##u << 16) \
        | ((unsigned long long)(unsigned short)p1##u << 32) \
        | ((unsigned long long)(unsigned short)p2##u << 48); }
    FORQ(STQ)
#undef STQ
}

// ---------------- kNN phase 2: exact top-12; output in SORTED index space ----------------
__global__ __launch_bounds__(256) void knn_topk_kernel(const float4* __restrict__ xw,
                                                       const unsigned long long* __restrict__ packed,
                                                       const unsigned short* __restrict__ ovf,
                                                       const int* __restrict__ oc,
                                                       const int* __restrict__ inv,
                                                       int* __restrict__ knn_idx) {
    const int q = blockIdx.x * 256 + threadIdx.x;
    const float4 me = xw[q];
    const float qsq = me.w;
    float b0=3e38f,b1=3e38f,b2=3e38f,b3=3e38f,b4=3e38f,b5=3e38f,
          b6=3e38f,b7=3e38f,b8=3e38f,b9=3e38f,b10=3e38f,b11=3e38f;
    int   j0=-1,j1=-1,j2=-1,j3=-1,j4=-1,j5=-1,j6=-1,j7=-1,j8=-1,j9=-1,j10=-1,j11=-1;
#define KTEST(IDX) { int _i = (IDX); if (_i != q) { float4 cc = xw[_i]; \
    float dot = me.x*cc.x + me.y*cc.y + me.z*cc.z; \
    float d = fmaf(-2.0f, dot, qsq + cc.w);  /* EXACT ref formula */ \
    d = fmaxf(d, 0.0f); \
    if (d < b11) KINSERT(d, _i); } }
    for (int s = 0; s < KSEG; ++s) {
        unsigned long long v = packed[(size_t)s*NN + q];
        int c = (int)(v & 0xFFFFull);
        if (c > 0) KTEST((int)((v >> 16) & 0xFFFFull));
        if (c > 1) KTEST((int)((v >> 32) & 0xFFFFull));
        if (c > 2) KTEST((int)((v >> 48) & 0xFFFFull));
    }
    int no = oc[q]; if (no > OCAP) no = OCAP;
    for (int i = 0; i < no; ++i) KTEST((int)ovf[(size_t)q*OCAP + i]);
#undef KTEST
    // whole network runs in sorted space: row = inv[q], neighbors = inv[j_k]
    const int sq = inv[q];
    knn_idx[sq*KNN+0]=inv[j0];  knn_idx[sq*KNN+1]=inv[j1];  knn_idx[sq*KNN+2]=inv[j2];
    knn_idx[sq*KNN+3]=inv[j3];  knn_idx[sq*KNN+4]=inv[j4];  knn_idx[sq*KNN+5]=inv[j5];
    knn_idx[sq*KNN+6]=inv[j6];  knn_idx[sq*KNN+7]=inv[j7];  knn_idx[sq*KNN+8]=inv[j8];
    knn_idx[sq*KNN+9]=inv[j9];  knn_idx[sq*KNN+10]=inv[j10]; knn_idx[sq*KNN+11]=inv[j11];
}

// ---------------- weight convert+transpose to f16 [N][K] ----------------
__global__ __launch_bounds__(256) void convert_Wt_kernel(const float* __restrict__ W,
                                                         _Float16* __restrict__ Wt) {
    int e = blockIdx.x*256 + threadIdx.x;
    int l = e >> 16, r = e & 65535;
    int n = r >> 8, k = r & 255;
    Wt[(size_t)l*65536 + n*256 + k] = (_Float16)W[(size_t)l*65536 + k*256 + n];
}

__global__ __launch_bounds__(256) void convert_Bg_kernel(const float* __restrict__ Ws,
                                                         const float* __restrict__ Wn,
                                                         _Float16* __restrict__ Bg) {
    int e = blockIdx.x*256 + threadIdx.x;
    int l = e / 73728, r = e % 73728;
    int n = r / 384, k = r % 384;
    float v = (k < 192) ? Ws[(size_t)l*36864 + k*192 + n]
                        : Wn[(size_t)l*36864 + (k-192)*192 + n];
    Bg[(size_t)l*73728 + (size_t)n*384 + k] = (_Float16)v;
}

__global__ __launch_bounds__(256) void convert_Wgo_kernel(const float* __restrict__ Wg_out,
                                                          _Float16* __restrict__ Wgo) {
    int e = blockIdx.x*256 + threadIdx.x;
    int n = e / 192, k = e % 192;
    Wgo[e] = (_Float16)Wg_out[k*256 + n];
}

// ---------------- fourier features + both input layers (sorted space, f16 out) ----------------
__global__ __launch_bounds__(256) void fourier_input_kernel(
    const float4* __restrict__ xs, const float* __restrict__ Bf,
    const float* __restrict__ W_in, const float* __restrict__ b_in,
    const float* __restrict__ Wg_in, const float* __restrict__ bg_in,
    _Float16* __restrict__ h0, _Float16* __restrict__ g0) {
    const int n = blockIdx.x * 256 + threadIdx.x;   // n = sorted gid
    const float4 p = xs[n];
    const float x0 = p.x, x1 = p.y, x2 = p.z;
    float ff[FF];
#pragma unroll
    for (int sm = 0; sm < 24; ++sm) {
        int s = sm >> 3, m = sm & 7;
        float ph = x0*Bf[s*24 + m] + x1*Bf[s*24 + 8 + m] + x2*Bf[s*24 + 16 + m];
        float sv, cv; sincosf(ph, &sv, &cv);
        ff[sm] = sv; ff[24 + sm] = cv;
    }
    {
        const float4* W4 = (const float4*)W_in;
        const float4* b4 = (const float4*)b_in;
#pragma unroll 2
        for (int j4 = 0; j4 < WIDTH/4; ++j4) {
            float4 acc = b4[j4];
#pragma unroll
            for (int k = 0; k < FF; ++k) {
                float4 w = W4[k*(WIDTH/4) + j4]; float f = ff[k];
                acc.x = fmaf(f, w.x, acc.x); acc.y = fmaf(f, w.y, acc.y);
                acc.z = fmaf(f, w.z, acc.z); acc.w = fmaf(f, w.w, acc.w);
            }
            half4 o;
            o[0] = (_Float16)silu_f(acc.x); o[1] = (_Float16)silu_f(acc.y);
            o[2] = (_Float16)silu_f(acc.z); o[3] = (_Float16)silu_f(acc.w);
            *(half4*)&h0[(size_t)n*WIDTH + j4*4] = o;
        }
    }
    {
        const float4* W4 = (const float4*)Wg_in;
        const float4* b4 = (const float4*)bg_in;
#pragma unroll 2
        for (int j4 = 0; j4 < GW/4; ++j4) {
            float4 acc = b4[j4];
#pragma unroll
            for (int k = 0; k < FF; ++k) {
                float4 w = W4[k*(GW/4) + j4]; float f = ff[k];
                acc.x = fmaf(f, w.x, acc.x); acc.y = fmaf(f, w.y, acc.y);
                acc.z = fmaf(f, w.z, acc.z); acc.w = fmaf(f, w.w, acc.w);
            }
            half4 o;
            o[0] = (_Float16)silu_f(acc.x); o[1] = (_Float16)silu_f(acc.y);
            o[2] = (_Float16)silu_f(acc.z); o[3] = (_Float16)silu_f(acc.w);
            *(half4*)&g0[(size_t)n*GW + j4*4] = o;
        }
    }
}

// ---------------- gather + mean over 12 neighbors (sorted space: L2-local) ----------------
__global__ __launch_bounds__(192) void gather_mean_kernel(const _Float16* __restrict__ g,
                                                          const int* __restrict__ idx,
                                                          _Float16* __restrict__ agg) {
    __shared__ int nb[KNN];
    const int n = blockIdx.x;
    if (threadIdx.x < KNN) nb[threadIdx.x] = idx[n*KNN + threadIdx.x];
    __syncthreads();
    float acc = 0.0f;
#pragma unroll
    for (int k = 0; k < KNN; ++k) acc += (float)g[(size_t)nb[k]*GW + threadIdx.x];
    agg[(size_t)n*GW + threadIdx.x] = (_Float16)(acc * (1.0f/12.0f));
}

// ---------------- FiLM params ----------------
__global__ __launch_bounds__(256) void film_kernel(const float* __restrict__ cond,
                                                   const float* __restrict__ Wf_g,
                                                   const float* __restrict__ bf_g,
                                                   const float* __restrict__ Wf_b,
                                                   const float* __restrict__ bf_b,
                                                   float* __restrict__ film) {
    const int l = blockIdx.x, j = threadIdx.x;
    float g = bf_g[l*WIDTH + j], b = bf_b[l*WIDTH + j];
    for (int c = 0; c < 64; ++c) {
        float cv = cond[c];
        g = fmaf(cv, Wf_g[(size_t)(l*64 + c)*WIDTH + j], g);
        b = fmaf(cv, Wf_b[(size_t)(l*64 + c)*WIDTH + j], b);
    }
    film[l*2*WIDTH + j]         = 1.0f + g;
    film[l*2*WIDTH + WIDTH + j] = b;
}

// ---------------- f16 MFMA GEMM: BM=128, BN=64, 4 waves ----------------
template<int EPI>
__global__ __launch_bounds__(256) void gemm_mfma(
    const _Float16* __restrict__ A1, const _Float16* __restrict__ A2,
    const _Float16* __restrict__ Bt, int K1, int Ktot, int NC,
    const float* __restrict__ bias, const float* __restrict__ film,
    const _Float16* __restrict__ h0, _Float16* __restrict__ C, int addSkip) {
    __shared__ _Float16 As[128*40];
    __shared__ _Float16 Bs[64*40];
    const int tid = threadIdx.x;
    const int bm = blockIdx.x * 128, bn = blockIdx.y * 64;
    const int wid = tid >> 6, lane = tid & 63;
    const int wm = (wid & 1) * 64, wn = (wid >> 1) * 32;
    const int m16 = lane & 15, kq = lane >> 4;
    const int ar = tid >> 1, ah = tid & 1;
    const int br = tid >> 2, bq = tid & 3;
    f4 acc[4][2];
#pragma unroll
    for (int i = 0; i < 4; ++i)
#pragma unroll
        for (int j = 0; j < 2; ++j) acc[i][j] = (f4){0.f, 0.f, 0.f, 0.f};

    for (int kc = 0; kc < Ktot; kc += 32) {
        const _Float16* Asrc; int kl, ldA;
        if (kc < K1) { Asrc = A1; kl = kc;      ldA = K1; }
        else         { Asrc = A2; kl = kc - K1; ldA = Ktot - K1; }
        {
            const float4* src = (const float4*)&Asrc[(size_t)(bm + ar)*ldA + kl + ah*16];
            *(float4*)&As[ar*40 + ah*16]     = src[0];
            *(float4*)&As[ar*40 + ah*16 + 8] = src[1];
        }
        *(float4*)&Bs[br*40 + bq*8] = *(const float4*)&Bt[(size_t)(bn + br)*Ktot + kc + bq*8];
        __syncthreads();
        half8 af[4], bf[2];
#pragma unroll
        for (int mt = 0; mt < 4; ++mt) af[mt] = *(half8*)&As[(wm + mt*16 + m16)*40 + kq*8];
#pragma unroll
        for (int nt = 0; nt < 2; ++nt) bf[nt] = *(half8*)&Bs[(wn + nt*16 + m16)*40 + kq*8];
#pragma unroll
        for (int mt = 0; mt < 4; ++mt)
#pragma unroll
            for (int nt = 0; nt < 2; ++nt)
                acc[mt][nt] = __builtin_amdgcn_mfma_f32_16x16x32_f16(af[mt], bf[nt], acc[mt][nt], 0, 0, 0);
        __syncthreads();
    }

#pragma unroll
    for (int mt = 0; mt < 4; ++mt) {
#pragma unroll
        for (int nt = 0; nt < 2; ++nt) {
            int col = bn + wn + nt*16 + m16;
#pragma unroll
            for (int r = 0; r < 4; ++r) {
                int row = bm + wm + mt*16 + kq*4 + r;
                float v = acc[mt][nt][r];
                if (EPI == 0) {
                    v = silu_f(v + bias[col]);
                } else if (EPI == 1) {
                    v = fmaf(v + bias[col], film[col], film[NC + col]);
                    v = silu_f(v);
                    if (addSkip) v += (float)h0[(size_t)row*NC + col];
                } else {
                    v += (float)h0[(size_t)row*NC + col];
                }
                C[(size_t)row*NC + col] = (_Float16)v;
            }
        }
    }
}

// ---------------- output head: scatter back to original order ----------------
__global__ __launch_bounds__(256) void out_kernel(const _Float16* __restrict__ h,
                                                  const float* __restrict__ W_out,
                                                  const float* __restrict__ b_out,
                                                  const int* __restrict__ sidx,
                                                  float* __restrict__ out) {
    const int n = blockIdx.x * 256 + threadIdx.x;   // sorted gid
    float a0 = 0.f, a1 = 0.f, a2 = 0.f;
#pragma unroll 4
    for (int k8 = 0; k8 < WIDTH/8; ++k8) {
        half8 v = *(const half8*)&h[(size_t)n*WIDTH + k8*8];
#pragma unroll
        for (int u = 0; u < 8; ++u) {
            float f = (float)v[u]; int k = k8*8 + u;
            a0 = fmaf(f, W_out[k*3+0], a0);
            a1 = fmaf(f, W_out[k*3+1], a1);
            a2 = fmaf(f, W_out[k*3+2], a2);
        }
    }
    const int q = sidx[n];
    out[q*3+0] = (a0 + b_out[0]) * 0.01f;
    out[q*3+1] = (a1 + b_out[1]) * 0.01f;
    out[q*3+2] = (a2 + b_out[2]) * 0.01f;
}

extern "C" void kernel_launch(void* const* d_in, const int* in_sizes, int n_in,
                              void* d_out, int out_size, void* d_ws, size_t ws_size,
                              hipStream_t stream) {
    const float* x      = (const float*)d_in[0];
    const float* cond   = (const float*)d_in[1];
    const float* Bf     = (const float*)d_in[2];
    const float* W_in   = (const float*)d_in[3];
    const float* b_in   = (const float*)d_in[4];
    const float* Wg_in  = (const float*)d_in[5];
    const float* bg_in  = (const float*)d_in[6];
    const float* Ws     = (const float*)d_in[7];
    const float* Wn     = (const float*)d_in[8];
    const float* bg     = (const float*)d_in[9];
    const float* Wg_out = (const float*)d_in[10];
    const float* W      = (const float*)d_in[11];
    const float* bmlp   = (const float*)d_in[12];
    const float* Wf_g   = (const float*)d_in[13];
    const float* bf_g   = (const float*)d_in[14];
    const float* Wf_b   = (const float*)d_in[15];
    const float* bf_b   = (const float*)d_in[16];
    const float* W_out  = (const float*)d_in[17];
    const float* b_out  = (const float*)d_in[18];
    float* out = (float*)d_out;

    char* ws = (char*)d_ws;
    int*       knn_idx = (int*)      (ws + 0);          //  3,145,728 (sorted space)
    float4*    xw      = (float4*)   (ws + 3145728);    //  1,048,576
    float*     film    = (float*)    (ws + 4194304);    //     14,336
    _Float16*  Bg_t    = (_Float16*) (ws + 4210688);    //    589,824
    _Float16*  Wgo_t   = (_Float16*) (ws + 4800512);    //     98,304
    _Float16*  Wt      = (_Float16*) (ws + 4898816);    //    917,504
    _Float16*  h0      = (_Float16*) (ws + 5816320);    // 33,554,432 (f16) -> 39,370,752
    // kNN scratch overlays h0 (dead before fourier_input writes h0):
    int*       cnt     = (int*)      (ws + 5816320);    // 28,311,552 (192^3 SAT in place)
    float*     seed    = (float*)    (ws + 34127872);   //    262,144 -> 34,390,016
    int*       pcell   = (int*)      (ws + 34390016);   //    262,144 -> 34,652,160
    int*       prank   = (int*)      (ws + 34652160);   //    262,144 -> 34,914,304
    int*       cnt2    = (int*)      (ws + 34914304);   //  1,048,576 -> 35,962,880
    int*       start2  = (int*)      (ws + 35962880);   //  1,048,576 -> 37,011,456
    int*       sums    = (int*)      (ws + 37011456);   //      1,024 -> 37,012,480
    float*     seedT   = (float*)    (ws + 37012480);   //    262,144 -> 37,274,624 < h0 end
    // packed/ovf/oc overlay g_a..agg (dead during kNN):
    unsigned long long* packed = (unsigned long long*)(ws + 39370752);   // 16,777,216 -> 56,147,968
    unsigned short*     ovf    = (unsigned short*)    (ws + 56147968);   // 50,331,648 -> 106,479,616
    int*                oc     = (int*)               (ws + 106479616);  //    262,144 -> 106,741,760
    _Float16*  g_a     = (_Float16*) (ws + 39370752);   // 25,165,824
    _Float16*  g_b     = (_Float16*) (ws + 64536576);   // 25,165,824
    _Float16*  agg     = (_Float16*) (ws + 89702400);   // 25,165,824
    _Float16*  hA      = (_Float16*) (ws + 114868224);  // 33,554,432
    _Float16*  hB      = (_Float16*) (ws + 148422656);  // 33,554,432 -> 181,977,088
    // persistent tail (must survive the whole pipeline; NOT in any overlay):
    float4*    xs      = (float4*)   (ws + 181977088);  //  1,048,576 -> 183,025,664
    int*       sidx    = (int*)      (ws + 183025664);  //    262,144 -> 183,287,808
    int*       inv     = (int*)      (ws + 183287808);  //    262,144 -> 183,549,952

    // --- kNN: SAT seed -> sort(+inv) -> tighten -> packed brute scan -> top-12 ---
    prep_xw_kernel<<<NN/256, 256, 0, stream>>>(x, xw);
    zero_cnt_kernel<<<GC3/1024, 256, 0, stream>>>(cnt);
    hist_kernel<<<NN/256, 256, 0, stream>>>(xw, cnt);
    satx_kernel<<<GC*GC/256, 256, 0, stream>>>(cnt);
    saty_kernel<<<GC*GC/256, 256, 0, stream>>>(cnt);
    satz_kernel<<<GC*GC/256, 256, 0, stream>>>(cnt);
    seed_kernel<<<NN/256, 256, 0, stream>>>(xw, cnt, seed);
    zero_cnt_kernel<<<GC2_3/1024, 256, 0, stream>>>(cnt2);
    hist2_kernel<<<NN/256, 256, 0, stream>>>(xw, cnt2, pcell, prank);
    scan1_kernel<<<GC2_3/1024, 256, 0, stream>>>(cnt2, start2, sums);
    scan2_kernel<<<1, 256, 0, stream>>>(sums);
    scan3_kernel<<<GC2_3/256, 256, 0, stream>>>(start2, sums);
    scatter_kernel<<<NN/256, 256, 0, stream>>>(xw, pcell, prank, start2, xs, sidx, inv);
    tighten_kernel<<<NN/256, 256, 0, stream>>>(xs, sidx, seed, seedT);
    zero_cnt_kernel<<<NN/1024, 256, 0, stream>>>(oc);     // FULL oc zero
    knn_pairs_kernel<<<dim3(NN/(256*QPT), KSEG), 256, 0, stream>>>(xw, seedT, packed, ovf, oc);
    knn_topk_kernel<<<NN/256, 256, 0, stream>>>(xw, packed, ovf, oc, inv, knn_idx);

    // --- network (all rows in sorted space; neighbors L2-local) ---
    film_kernel<<<DEPTH, 256, 0, stream>>>(cond, Wf_g, bf_g, Wf_b, bf_b, film);
    convert_Wt_kernel<<<DEPTH*65536/256, 256, 0, stream>>>(W, Wt);
    convert_Bg_kernel<<<GLAYERS*73728/256, 256, 0, stream>>>(Ws, Wn, Bg_t);
    convert_Wgo_kernel<<<256*192/256, 256, 0, stream>>>(Wg_out, Wgo_t);
    fourier_input_kernel<<<NN/256, 256, 0, stream>>>(xs, Bf, W_in, b_in, Wg_in, bg_in, h0, g_a);

    _Float16* gin = g_a; _Float16* gout = g_b;
    for (int l = 0; l < GLAYERS; ++l) {
        gather_mean_kernel<<<NN, GW, 0, stream>>>(gin, knn_idx, agg);
        gemm_mfma<0><<<dim3(NN/128, GW/64), 256, 0, stream>>>(
            gin, agg, Bg_t + (size_t)l*73728, GW, 2*GW, GW,
            bg + l*GW, nullptr, nullptr, gout, 0);
        _Float16* t = gin; gin = gout; gout = t;
    }
    // gin == g_a (4 swaps). inject: hA = h0 + gin @ Wg_out
    gemm_mfma<2><<<dim3(NN/128, WIDTH/64), 256, 0, stream>>>(
        gin, nullptr, Wgo_t, GW, GW, WIDTH, nullptr, nullptr, h0, hA, 0);

    _Float16* hin = hA; _Float16* hout = hB;
    for (int l = 0; l < DEPTH; ++l) {
        int skip = (l == 2 || l == 5) ? 1 : 0;   // SKIPS=(3,6): after layers idx 2,5
        gemm_mfma<1><<<dim3(NN/128, WIDTH/64), 256, 0, stream>>>(
            hin, nullptr, Wt + (size_t)l*65536, WIDTH, WIDTH, WIDTH,
            bmlp + l*WIDTH, film + l*2*WIDTH, h0, hout, skip);
        _Float16* t = hin; hin = hout; hout = t;
    }
    out_kernel<<<NN/256, 256, 0, stream>>>(hin, W_out, b_out, sidx, out);
}